// Round 4
// baseline (830.605 us; speedup 1.0000x reference)
//
#include <hip/hip_runtime.h>
#include <hip/hip_bf16.h>
#include <math.h>

#define NF 64
#define NH 8
#define HD 512   // NH * 64
#define SLOPE 0.2f

typedef __hip_bfloat16 bf16;
typedef short short8 __attribute__((ext_vector_type(8)));
typedef unsigned int uint4v __attribute__((ext_vector_type(4)));
typedef float f32x4 __attribute__((ext_vector_type(4)));
typedef float f32x2 __attribute__((ext_vector_type(2)));

__device__ __forceinline__ float b2f(bf16 v){ return __bfloat162float(v); }
__device__ __forceinline__ bf16 f2b(float v){ return __float2bfloat16(v); }
__device__ __forceinline__ float us2f(unsigned short u){
  union{ unsigned int i; float f; } c; c.i = ((unsigned int)u) << 16; return c.f;
}
// unpack packed 2xbf16 dword -> f32 (low / high element)
__device__ __forceinline__ float lo16(unsigned int u){
  union{ unsigned int i; float f; } c; c.i = u << 16; return c.f;
}
__device__ __forceinline__ float hi16(unsigned int u){
  union{ unsigned int i; float f; } c; c.i = u & 0xFFFF0000u; return c.f;
}
// round-to-nearest-even f32 -> bf16 bits
__device__ __forceinline__ unsigned short f2b_rne(float v){
  union{ float f; unsigned int i; } c; c.f = v;
  unsigned int b = c.i + 0x7FFF + ((c.i >> 16) & 1);
  return (unsigned short)(b >> 16);
}
__device__ __forceinline__ f32x4 mfma16(short8 a, short8 b, f32x4 c){
  return __builtin_amdgcn_mfma_f32_16x16x32_bf16(a, b, c, 0, 0, 0);
}

// ---------- weight pre-pack kernels (tiny, run once per launch) ----------
// B-fragment layout for mfma_f32_16x16x32_bf16: b[j] = B[(lane>>4)*8+j][lane&15]
// Packed as [term(hi=0,lo=1)][ks][frag][lane][j] -> coalesced short8 per lane.

// GEMM1: B = [W_att heads (512 cols) | W@a_src (8) | W@a_dst (8)] : 64 x 528, 33 frags, 2 ks
__global__ void k_prep1(const float* __restrict__ Watt, const float* __restrict__ aatt,
                        short* __restrict__ Bp1){
  int f = blockIdx.x >> 1, ks = blockIdx.x & 1;
  int lane = threadIdx.x;
  int kg = lane >> 4, cl = lane & 15;
  int col = f * 16 + cl;
  for (int j = 0; j < 8; j++){
    int k = ks * 32 + kg * 8 + j;
    float val;
    if (col < 512){
      val = Watt[(size_t)(col >> 6) * 4096 + k * 64 + (col & 63)];
    } else {
      int h = (col - 512) & 7;
      const float* arow = aatt + h * 128 + ((col >= 520) ? 64 : 0);
      const float* wrow = Watt + (size_t)h * 4096 + k * 64;
      float s = 0.f;
      for (int d = 0; d < 64; d++) s += wrow[d] * arow[d];
      val = s;
    }
    unsigned short hu = f2b_rne(val);
    float lof = val - us2f(hu);
    Bp1[((size_t)(ks * 33) + f) * 512 + lane * 8 + j]       = (short)hu;
    Bp1[((size_t)((2 + ks) * 33) + f) * 512 + lane * 8 + j] = (short)f2b_rne(lof);
  }
}

// GEMM2: B = [Wout (64 cols) | Wout@aout_s | Wout@aout_d | pad] : 512 x 80, 5 frags, 16 ks
__global__ void k_prep2(const float* __restrict__ Wout, const float* __restrict__ aout,
                        short* __restrict__ Bp2){
  int f = blockIdx.x >> 4, ks = blockIdx.x & 15;
  int lane = threadIdx.x;
  int kg = lane >> 4, cl = lane & 15;
  int col = f * 16 + cl;
  for (int j = 0; j < 8; j++){
    int k = ks * 32 + kg * 8 + j;
    float val = 0.f;
    if (col < 64){
      val = Wout[(size_t)k * 64 + col];
    } else if (col == 64 || col == 65){
      const float* arow = aout + ((col == 65) ? 64 : 0);
      const float* wrow = Wout + (size_t)k * 64;
      float s = 0.f;
      for (int d = 0; d < 64; d++) s += wrow[d] * arow[d];
      val = s;
    }
    unsigned short hu = f2b_rne(val);
    float lof = val - us2f(hu);
    Bp2[((size_t)(ks * 5) + f) * 512 + lane * 8 + j]        = (short)hu;
    Bp2[((size_t)((16 + ks) * 5) + f) * 512 + lane * 8 + j] = (short)f2b_rne(lof);
  }
}

// MLP1: B = W1 : 64 x 640, 40 frags, 2 ks
__global__ void k_prep3(const float* __restrict__ W1, short* __restrict__ Bp3){
  int f = blockIdx.x >> 1, ks = blockIdx.x & 1;
  int lane = threadIdx.x;
  int kg = lane >> 4, cl = lane & 15;
  int col = f * 16 + cl;
  for (int j = 0; j < 8; j++){
    int k = ks * 32 + kg * 8 + j;
    float val = W1[(size_t)k * 640 + col];
    unsigned short hu = f2b_rne(val);
    float lof = val - us2f(hu);
    Bp3[((size_t)(ks * 40) + f) * 512 + lane * 8 + j]       = (short)hu;
    Bp3[((size_t)((2 + ks) * 40) + f) * 512 + lane * 8 + j] = (short)f2b_rne(lof);
  }
}

// ---------- GEMM1 via MFMA: H = x @ Wcat (alpha folded as extra cols) ----------
__global__ void __launch_bounds__(256)
k_gemm1_mfma(const float* __restrict__ x, const short* __restrict__ Bp1,
             bf16* __restrict__ Hb, float* __restrict__ a1s, float* __restrict__ a1d,
             int n_nodes){
  __shared__ short xsh[16][72];   // hi bf16, stride 144B: 16B-aligned, 2-way banks (free)
  __shared__ short xsl[16][72];   // lo bf16
  __shared__ short Ht[16][520];   // output transpose buffer for coalesced Hb write
  int n0 = blockIdx.x * 16;
  int t = threadIdx.x;
  for (int i = t; i < 16 * 64; i += 256){
    int r = i >> 6, c = i & 63;
    int nn = n0 + r;
    float v = (nn < n_nodes) ? x[(size_t)nn * NF + c] : 0.f;
    unsigned short hu = f2b_rne(v);
    float lof = v - us2f(hu);
    xsh[r][c] = (short)hu;
    xsl[r][c] = (short)f2b_rne(lof);
  }
  __syncthreads();
  int wid = t >> 6, lane = t & 63;
  int rowa = lane & 15, kg = lane >> 4, cl = lane & 15;
  short8 ah[2], al[2];
  #pragma unroll
  for (int ks = 0; ks < 2; ks++){
    ah[ks] = *reinterpret_cast<const short8*>(&xsh[rowa][ks * 32 + kg * 8]);
    al[ks] = *reinterpret_cast<const short8*>(&xsl[rowa][ks * 32 + kg * 8]);
  }
  int nf = (wid == 3) ? 9 : 8;          // wave 3 also does the alpha frag (f=32)
  for (int f0 = 0; f0 < nf; f0++){
    int f = wid * 8 + f0;
    f32x4 acc = {0.f, 0.f, 0.f, 0.f};
    #pragma unroll
    for (int ks = 0; ks < 2; ks++){
      short8 b_h = *reinterpret_cast<const short8*>(Bp1 + ((size_t)(ks * 33) + f) * 512 + lane * 8);
      short8 b_l = *reinterpret_cast<const short8*>(Bp1 + ((size_t)((2 + ks) * 33) + f) * 512 + lane * 8);
      acc = mfma16(ah[ks], b_h, acc);   // hi*hi
      acc = mfma16(al[ks], b_h, acc);   // lo*hi
      acc = mfma16(ah[ks], b_l, acc);   // hi*lo
    }
    if (f < 32){
      #pragma unroll
      for (int reg = 0; reg < 4; reg++)
        Ht[kg * 4 + reg][f * 16 + cl] = (short)f2b_rne(acc[reg]);
    } else {
      #pragma unroll
      for (int reg = 0; reg < 4; reg++){
        int nn = n0 + kg * 4 + reg;
        if (nn < n_nodes){
          if (cl < 8) a1s[nn * NH + cl] = acc[reg];
          else        a1d[nn * NH + (cl - 8)] = acc[reg];
        }
      }
    }
  }
  __syncthreads();
  for (int i = t; i < 16 * 64; i += 256){
    int r = i >> 6, c8 = (i & 63) * 8;
    int nn = n0 + r;
    if (nn < n_nodes)
      *reinterpret_cast<short8*>(Hb + (size_t)nn * HD + c8) =
        *reinterpret_cast<const short8*>(&Ht[r][c8]);
  }
}

// ---------- CSR build ----------
__global__ void k_count(const int* __restrict__ row, int* __restrict__ cnt, int E){
  int e = blockIdx.x * blockDim.x + threadIdx.x;
  if (e < E) atomicAdd(&cnt[row[e]], 1);
}

__global__ void k_scan_a(const int* __restrict__ cnt, int* __restrict__ incl,
                         int* __restrict__ bsum, int n){
  __shared__ int s[1024];
  int i = blockIdx.x * 1024 + threadIdx.x;
  int v = (i < n) ? cnt[i] : 0;
  s[threadIdx.x] = v;
  __syncthreads();
  for (int d = 1; d < 1024; d <<= 1){
    int tv = (threadIdx.x >= d) ? s[threadIdx.x - d] : 0;
    __syncthreads();
    s[threadIdx.x] += tv;
    __syncthreads();
  }
  if (i < n) incl[i] = s[threadIdx.x];
  if (threadIdx.x == 1023) bsum[blockIdx.x] = s[1023];
}

__global__ void k_scan_b(const int* __restrict__ bsum, int* __restrict__ boff, int nb){
  __shared__ int s[128];
  int t = threadIdx.x;
  if (nb <= 128){
    int v = (t < nb) ? bsum[t] : 0;
    s[t] = v;
    __syncthreads();
    for (int d = 1; d < 128; d <<= 1){
      int tv = (t >= d) ? s[t - d] : 0;
      __syncthreads();
      s[t] += tv;
      __syncthreads();
    }
    if (t < nb) boff[t] = s[t] - v;   // exclusive
  } else if (t == 0){
    int run = 0;
    for (int b = 0; b < nb; b++){ boff[b] = run; run += bsum[b]; }
  }
}

__global__ void k_scan_c(const int* __restrict__ incl, const int* __restrict__ cnt,
                         const int* __restrict__ boff, int* __restrict__ rowptr,
                         int* __restrict__ wptr, int n){
  int i = blockIdx.x * 1024 + threadIdx.x;
  if (i < n){
    int start = incl[i] - cnt[i] + boff[blockIdx.x];
    rowptr[i] = start;
    wptr[i]   = start;
  }
}

__global__ void k_scatter(const int* __restrict__ row, const int* __restrict__ col,
                          int* __restrict__ wptr, int* __restrict__ scol, int E){
  int e = blockIdx.x * blockDim.x + threadIdx.x;
  if (e < E){
    int r = row[e];
    int pos = atomicAdd(&wptr[r], 1);
    scol[pos] = col[e];
  }
}

// ---------- sort each CSR row's columns (wave bitonic, <=64 elems) ----------
__global__ void k_sortrows(const int* __restrict__ rowptr, const int* __restrict__ cnt,
                           int* __restrict__ scol, int n_nodes){
  int n = blockIdx.x * 4 + (threadIdx.x >> 6);
  int lane = threadIdx.x & 63;
  if (n >= n_nodes) return;
  int c = cnt[n];
  if (c < 2 || c > 64) return;
  int beg = rowptr[n];
  int v = (lane < c) ? scol[beg + lane] : 0x7FFFFFFF;
  #pragma unroll
  for (int k = 2; k <= 64; k <<= 1){
    #pragma unroll
    for (int j = k >> 1; j > 0; j >>= 1){
      int o = __shfl_xor(v, j);
      bool dirUp = ((lane & k) == 0);
      bool takeMin = (((lane & j) == 0) == dirUp);
      int mn = (v < o) ? v : o;
      int mx = (v < o) ? o : v;
      v = takeMin ? mn : mx;
    }
  }
  if (lane < c) scol[beg + lane] = v;
}

// ---------- fused agg1 + MFMA GEMM2 (alpha2 folded as 2 extra cols) ----------
// 8 nodes/block, 512 threads (8 waves).
// Phase 1: cols held in registers (1 coalesced load + shfl), masked 8-wide
// unroll -> 16 outstanding loads, no serial tail. Masked edges re-read edge 0's
// row (L2-hot) with weight forced to 0.
__global__ void __launch_bounds__(512, 2)
k_agg1_gemm2(const bf16* __restrict__ Hb, const float* __restrict__ a1s,
             const float* __restrict__ a1d, const int* __restrict__ rowptr,
             const int* __restrict__ cnt, const int* __restrict__ scol,
             const short* __restrict__ Bp2, bf16* __restrict__ h2b,
             float* __restrict__ a2s, float* __restrict__ a2d, int n_nodes){
  __shared__ short xh[8][528];   // elu(h_prime) hi bf16
  __shared__ short xl[8][528];   // lo bf16
  int n0   = blockIdx.x * 8;
  int wid  = threadIdx.x >> 6;
  int lane = threadIdx.x & 63;
  int hsel = lane >> 3;
  int n = n0 + wid;

  if (n < n_nodes){
    float asrc = a1s[n * NH + hsel];
    int beg = rowptr[n], deg = cnt[n];
    f32x2 acc2[4] = {{0.f,0.f},{0.f,0.f},{0.f,0.f},{0.f,0.f}};
    float rsum = 0.f;
    if (deg <= 64){
      int myc = scol[beg + ((lane < deg) ? lane : 0)];
      int iters = (deg + 7) >> 3;
      for (int it = 0; it < iters; it++){
        int kb = it * 8;
        int c[8];
        #pragma unroll
        for (int u = 0; u < 8; u++){
          int idx = kb + u;
          c[u] = __shfl(myc, (idx < deg) ? idx : 0);
        }
        uint4v hb[8];
        #pragma unroll
        for (int u = 0; u < 8; u++)
          hb[u] = *reinterpret_cast<const uint4v*>(Hb + (size_t)c[u] * HD + lane * 8);
        float ad[8];
        #pragma unroll
        for (int u = 0; u < 8; u++)
          ad[u] = a1d[(c[u] << 3) + hsel];
        #pragma unroll
        for (int u = 0; u < 8; u++){
          float s = asrc + ad[u];
          float l = fmaxf(s, SLOPE * s);
          float e = __expf(-l);
          e = (kb + u < deg) ? e : 0.f;
          rsum += e;
          f32x2 ev = {e, e};
          #pragma unroll
          for (int d = 0; d < 4; d++){
            f32x2 hv = {lo16(hb[u][d]), hi16(hb[u][d])};
            acc2[d] += ev * hv;
          }
        }
      }
    } else {
      // generic fallback (deg > 64: not expected for this input)
      for (int k = beg; k < beg + deg; ++k){
        int c0 = scol[k];
        uint4v h0 = *reinterpret_cast<const uint4v*>(Hb + (size_t)c0 * HD + lane * 8);
        float s0 = asrc + a1d[(c0 << 3) + hsel];
        float l0 = fmaxf(s0, SLOPE * s0);
        float e0 = __expf(-l0);
        rsum += e0;
        f32x2 ev = {e0, e0};
        #pragma unroll
        for (int d = 0; d < 4; d++){
          f32x2 hv = {lo16(h0[d]), hi16(h0[d])};
          acc2[d] += ev * hv;
        }
      }
    }
    float inv = 1.f / rsum;
    short8 hv8, lv8;
    #pragma unroll
    for (int jj = 0; jj < 8; jj++){
      float v = acc2[jj >> 1][jj & 1] * inv;
      v = (v > 0.f) ? v : (__expf(v) - 1.f);   // elu
      unsigned short hu = f2b_rne(v);
      float lof = v - us2f(hu);
      hv8[jj] = (short)hu;
      lv8[jj] = (short)f2b_rne(lof);
    }
    *reinterpret_cast<short8*>(&xh[wid][lane * 8]) = hv8;
    *reinterpret_cast<short8*>(&xl[wid][lane * 8]) = lv8;
  } else {
    short8 z = {0,0,0,0,0,0,0,0};
    *reinterpret_cast<short8*>(&xh[wid][lane * 8]) = z;
    *reinterpret_cast<short8*>(&xl[wid][lane * 8]) = z;
  }
  __syncthreads();

  // ---- phase 2+3: MFMA GEMM2; waves 0-3 -> h2b cols, wave 4 -> alpha2 ----
  if (wid < 5){
    int rowa = lane & 7;            // A rows 8-15 duplicate 0-7 (outputs discarded)
    int kg   = lane >> 4;
    f32x4 acc = {0.f, 0.f, 0.f, 0.f};
    #pragma unroll 4
    for (int ks = 0; ks < 16; ks++){
      short8 a_h = *reinterpret_cast<const short8*>(&xh[rowa][ks * 32 + kg * 8]);
      short8 a_l = *reinterpret_cast<const short8*>(&xl[rowa][ks * 32 + kg * 8]);
      short8 b_h = *reinterpret_cast<const short8*>(Bp2 + ((size_t)(ks * 5) + wid) * 512 + lane * 8);
      short8 b_l = *reinterpret_cast<const short8*>(Bp2 + ((size_t)((16 + ks) * 5) + wid) * 512 + lane * 8);
      acc = mfma16(a_h, b_h, acc);
      acc = mfma16(a_l, b_h, acc);
      acc = mfma16(a_h, b_l, acc);
    }
    int cl = lane & 15;
    if (kg < 2){                    // D rows 0-7 = our 8 nodes
      #pragma unroll
      for (int reg = 0; reg < 4; reg++){
        int nn = n0 + kg * 4 + reg;
        if (nn < n_nodes){
          if (wid < 4){
            h2b[(size_t)nn * 64 + wid * 16 + cl] = f2b(acc[reg]);
          } else if (cl == 0){
            a2s[nn] = acc[reg];
          } else if (cl == 1){
            a2d[nn] = acc[reg];
          }
        }
      }
    }
  }
}

// ---------- aggregation layer 2: one wave per node, masked 8-wide unroll ----------
__global__ void k_agg2(const bf16* __restrict__ h2b, const float* __restrict__ a2s,
                       const float* __restrict__ a2d, const int* __restrict__ rowptr,
                       const int* __restrict__ cnt, const int* __restrict__ scol,
                       float* __restrict__ xo, int n_nodes){
  int n = blockIdx.x * 4 + (threadIdx.x >> 6);
  int lane = threadIdx.x & 63;
  if (n >= n_nodes) return;
  float asrc = a2s[n];
  int beg = rowptr[n], deg = cnt[n];
  float acc = 0.f, rsum = 0.f;
  if (deg <= 64){
    int myc = scol[beg + ((lane < deg) ? lane : 0)];
    int iters = (deg + 7) >> 3;
    for (int it = 0; it < iters; it++){
      int kb = it * 8;
      int c[8];
      #pragma unroll
      for (int u = 0; u < 8; u++){
        int idx = kb + u;
        c[u] = __shfl(myc, (idx < deg) ? idx : 0);
      }
      unsigned short hv[8];
      #pragma unroll
      for (int u = 0; u < 8; u++)
        hv[u] = *reinterpret_cast<const unsigned short*>(h2b + ((size_t)c[u] << 6) + lane);
      float ad[8];
      #pragma unroll
      for (int u = 0; u < 8; u++)
        ad[u] = a2d[c[u]];
      #pragma unroll
      for (int u = 0; u < 8; u++){
        float s = asrc + ad[u];
        float l = fmaxf(s, SLOPE * s);
        float e = __expf(-l);
        e = (kb + u < deg) ? e : 0.f;
        rsum += e;
        acc  += e * us2f(hv[u]);
      }
    }
  } else {
    for (int k = beg; k < beg + deg; ++k){
      int c0 = scol[k];
      float v0 = b2f(h2b[(size_t)c0 * 64 + lane]);
      float s0 = asrc + a2d[c0];
      float l0 = fmaxf(s0, SLOPE * s0);
      float e0 = __expf(-l0);
      rsum += e0;
      acc  += e0 * v0;
    }
  }
  float v = acc / rsum;
  v = (v > 0.f) ? v : (__expf(v) - 1.f);         // elu applied after layer 2
  xo[(size_t)n * 64 + lane] = v;
}

// ---------- MLP head: MFMA for W1 stage, 16 nodes/block ----------
__global__ void __launch_bounds__(256)
k_mlp(const float* __restrict__ xo, const short* __restrict__ Bp3,
      const float* __restrict__ b1, const float* __restrict__ W2,
      const float* __restrict__ b2, const float* __restrict__ W3,
      const float* __restrict__ b3, float* __restrict__ out, int n_nodes){
  __shared__ short xsh[16][72];
  __shared__ short xsl[16][72];
  __shared__ float z1[16][650];   // 650: conflict-free kg groups
  __shared__ float z2[16][10];
  int n0 = blockIdx.x * 16;
  int t  = threadIdx.x;
  for (int i = t; i < 16 * 64; i += 256){
    int r = i >> 6, c = i & 63;
    int nn = n0 + r;
    float v = (nn < n_nodes) ? xo[(size_t)nn * 64 + c] : 0.f;
    unsigned short hu = f2b_rne(v);
    float lof = v - us2f(hu);
    xsh[r][c] = (short)hu;
    xsl[r][c] = (short)f2b_rne(lof);
  }
  __syncthreads();
  int wid = t >> 6, lane = t & 63;
  int rowa = lane & 15, kg = lane >> 4, cl = lane & 15;
  short8 ah[2], al[2];
  #pragma unroll
  for (int ks = 0; ks < 2; ks++){
    ah[ks] = *reinterpret_cast<const short8*>(&xsh[rowa][ks * 32 + kg * 8]);
    al[ks] = *reinterpret_cast<const short8*>(&xsl[rowa][ks * 32 + kg * 8]);
  }
  for (int f0 = 0; f0 < 10; f0++){
    int f = wid * 10 + f0;
    f32x4 acc = {0.f, 0.f, 0.f, 0.f};
    #pragma unroll
    for (int ks = 0; ks < 2; ks++){
      short8 b_h = *reinterpret_cast<const short8*>(Bp3 + ((size_t)(ks * 40) + f) * 512 + lane * 8);
      short8 b_l = *reinterpret_cast<const short8*>(Bp3 + ((size_t)((2 + ks) * 40) + f) * 512 + lane * 8);
      acc = mfma16(ah[ks], b_h, acc);
      acc = mfma16(al[ks], b_h, acc);
      acc = mfma16(ah[ks], b_l, acc);
    }
    int cc = f * 16 + cl;
    float bb = b1[cc];
    #pragma unroll
    for (int reg = 0; reg < 4; reg++)
      z1[kg * 4 + reg][cc] = fmaxf(acc[reg] + bb, 0.f);
  }
  __syncthreads();
  {
    int g = t >> 4, sub = t & 15;
    float p[10];
    #pragma unroll
    for (int kk = 0; kk < 10; kk++) p[kk] = 0.f;
    for (int jj = 0; jj < 40; jj++){
      int j = sub + jj * 16;
      float v = z1[g][j];
      #pragma unroll
      for (int kk = 0; kk < 10; kk++) p[kk] += v * W2[j * 10 + kk];
    }
    #pragma unroll
    for (int kk = 0; kk < 10; kk++){
      #pragma unroll
      for (int m = 8; m; m >>= 1) p[kk] += __shfl_xor(p[kk], m);
    }
    if (sub == 0){
      #pragma unroll
      for (int kk = 0; kk < 10; kk++) z2[g][kk] = fmaxf(p[kk] + b2[kk], 0.f);
    }
  }
  __syncthreads();
  if (t < 16){
    int nn = n0 + t;
    if (nn < n_nodes){
      float acc = b3[0];
      #pragma unroll
      for (int kk = 0; kk < 10; kk++) acc += z2[t][kk] * W3[kk];
      out[nn] = 1.f / (1.f + __expf(-acc));
    }
  }
}

extern "C" void kernel_launch(void* const* d_in, const int* in_sizes, int n_in,
                              void* d_out, int out_size, void* d_ws, size_t ws_size,
                              hipStream_t stream){
  const float* x    = (const float*)d_in[0];
  const int*   ei   = (const int*)  d_in[1];
  const float* Watt = (const float*)d_in[2];
  const float* aatt = (const float*)d_in[3];
  const float* Wout = (const float*)d_in[4];
  const float* aout = (const float*)d_in[5];
  const float* W1   = (const float*)d_in[6];
  const float* b1   = (const float*)d_in[7];
  const float* W2   = (const float*)d_in[8];
  const float* b2   = (const float*)d_in[9];
  const float* W3   = (const float*)d_in[10];
  const float* b3   = (const float*)d_in[11];
  float* out = (float*)d_out;

  int N = in_sizes[0] / NF;
  int E = in_sizes[1] / 2;
  const int* row = ei;
  const int* col = ei + E;

  char* base = (char*)d_ws;
  size_t off = 0;
  auto alloc = [&](size_t bytes) -> void* {
    void* p = base + off;
    off = (off + bytes + 255) & ~(size_t)255;
    return p;
  };
  bf16*  Hb     = (bf16*) alloc((size_t)N * HD * 2);   // 102.4 MB
  bf16*  h2b    = (bf16*) alloc((size_t)N * 64 * 2);   // 12.8 MB
  float* xo     = (float*)alloc((size_t)N * 64 * 4);   // 25.6 MB
  float* a1s    = (float*)alloc((size_t)N * NH * 4);
  float* a1d    = (float*)alloc((size_t)N * NH * 4);
  float* a2s    = (float*)alloc((size_t)N * 4);
  float* a2d    = (float*)alloc((size_t)N * 4);
  int*   cnt    = (int*)  alloc((size_t)N * 4);
  int*   rowptr = (int*)  alloc((size_t)N * 4);
  int*   wptr   = (int*)  alloc((size_t)N * 4);
  int*   incl   = (int*)  alloc((size_t)N * 4);
  int    NB     = (N + 1023) / 1024;
  int*   bsum   = (int*)  alloc((size_t)NB * 4);
  int*   boff   = (int*)  alloc((size_t)NB * 4);
  int*   scol   = (int*)  alloc((size_t)E * 4);        // 6.4 MB
  short* Bp1    = (short*)alloc((size_t)4 * 33 * 512 * 2);   // 135 KB packed W_att|alpha1
  short* Bp2    = (short*)alloc((size_t)32 * 5 * 512 * 2);   // 160 KB packed Wout|alpha2
  short* Bp3    = (short*)alloc((size_t)4 * 40 * 512 * 2);   // 160 KB packed W1
  (void)ws_size; (void)n_in; (void)out_size;

  hipMemsetAsync(cnt, 0, (size_t)N * 4, stream);

  k_prep1     <<<66,              64, 0, stream>>>(Watt, aatt, Bp1);
  k_prep2     <<<80,              64, 0, stream>>>(Wout, aout, Bp2);
  k_prep3     <<<80,              64, 0, stream>>>(W1, Bp3);
  k_gemm1_mfma<<<(N + 15) / 16,  256, 0, stream>>>(x, Bp1, Hb, a1s, a1d, N);
  k_count     <<<(E + 255) / 256, 256, 0, stream>>>(row, cnt, E);
  k_scan_a    <<<NB,             1024, 0, stream>>>(cnt, incl, bsum, N);
  k_scan_b    <<<1,               128, 0, stream>>>(bsum, boff, NB);
  k_scan_c    <<<NB,             1024, 0, stream>>>(incl, cnt, boff, rowptr, wptr, N);
  k_scatter   <<<(E + 255) / 256, 256, 0, stream>>>(row, col, wptr, scol, E);
  k_sortrows  <<<(N + 3) / 4,     256, 0, stream>>>(rowptr, cnt, scol, N);
  k_agg1_gemm2<<<(N + 7) / 8,     512, 0, stream>>>(Hb, a1s, a1d, rowptr, cnt, scol,
                                                    Bp2, h2b, a2s, a2d, N);
  k_agg2      <<<(N + 3) / 4,     256, 0, stream>>>(h2b, a2s, a2d, rowptr, cnt, scol, xo, N);
  k_mlp       <<<(N + 15) / 16,  256, 0, stream>>>(xo, Bp3, b1, W2, b2, W3, b3, out, N);
}

// Round 5
// 749.315 us; speedup vs baseline: 1.1085x; 1.1085x over previous
//
#include <hip/hip_runtime.h>
#include <hip/hip_bf16.h>
#include <math.h>

#define NF 64
#define NH 8
#define HD 512   // NH * 64 (logical H width; stored as fp8 bytes)
#define SLOPE 0.2f

typedef __hip_bfloat16 bf16;
typedef short short8 __attribute__((ext_vector_type(8)));
typedef unsigned int u32x2 __attribute__((ext_vector_type(2)));
typedef float f32x4 __attribute__((ext_vector_type(4)));
typedef float f32x2 __attribute__((ext_vector_type(2)));

__device__ __forceinline__ float b2f(bf16 v){ return __bfloat162float(v); }
__device__ __forceinline__ bf16 f2b(float v){ return __float2bfloat16(v); }
__device__ __forceinline__ float us2f(unsigned short u){
  union{ unsigned int i; float f; } c; c.i = ((unsigned int)u) << 16; return c.f;
}
// round-to-nearest-even f32 -> bf16 bits
__device__ __forceinline__ unsigned short f2b_rne(float v){
  union{ float f; unsigned int i; } c; c.f = v;
  unsigned int b = c.i + 0x7FFF + ((c.i >> 16) & 1);
  return (unsigned short)(b >> 16);
}
__device__ __forceinline__ f32x4 mfma16(short8 a, short8 b, f32x4 c){
  return __builtin_amdgcn_mfma_f32_16x16x32_bf16(a, b, c, 0, 0, 0);
}

// ---------- weight pre-pack kernels (tiny, run once per launch) ----------
// B-fragment layout for mfma_f32_16x16x32_bf16: b[j] = B[(lane>>4)*8+j][lane&15]
// Packed as [term(hi=0,lo=1)][ks][frag][lane][j] -> coalesced short8 per lane.

// GEMM1: B = [W_att heads (512 cols) | W@a_src (8) | W@a_dst (8)] : 64 x 528, 33 frags, 2 ks
__global__ void k_prep1(const float* __restrict__ Watt, const float* __restrict__ aatt,
                        short* __restrict__ Bp1){
  int f = blockIdx.x >> 1, ks = blockIdx.x & 1;
  int lane = threadIdx.x;
  int kg = lane >> 4, cl = lane & 15;
  int col = f * 16 + cl;
  for (int j = 0; j < 8; j++){
    int k = ks * 32 + kg * 8 + j;
    float val;
    if (col < 512){
      val = Watt[(size_t)(col >> 6) * 4096 + k * 64 + (col & 63)];
    } else {
      int h = (col - 512) & 7;
      const float* arow = aatt + h * 128 + ((col >= 520) ? 64 : 0);
      const float* wrow = Watt + (size_t)h * 4096 + k * 64;
      float s = 0.f;
      for (int d = 0; d < 64; d++) s += wrow[d] * arow[d];
      val = s;
    }
    unsigned short hu = f2b_rne(val);
    float lof = val - us2f(hu);
    Bp1[((size_t)(ks * 33) + f) * 512 + lane * 8 + j]       = (short)hu;
    Bp1[((size_t)((2 + ks) * 33) + f) * 512 + lane * 8 + j] = (short)f2b_rne(lof);
  }
}

// GEMM2: B = [Wout (64 cols) | Wout@aout_s | Wout@aout_d | pad] : 512 x 80, 5 frags, 16 ks
__global__ void k_prep2(const float* __restrict__ Wout, const float* __restrict__ aout,
                        short* __restrict__ Bp2){
  int f = blockIdx.x >> 4, ks = blockIdx.x & 15;
  int lane = threadIdx.x;
  int kg = lane >> 4, cl = lane & 15;
  int col = f * 16 + cl;
  for (int j = 0; j < 8; j++){
    int k = ks * 32 + kg * 8 + j;
    float val = 0.f;
    if (col < 64){
      val = Wout[(size_t)k * 64 + col];
    } else if (col == 64 || col == 65){
      const float* arow = aout + ((col == 65) ? 64 : 0);
      const float* wrow = Wout + (size_t)k * 64;
      float s = 0.f;
      for (int d = 0; d < 64; d++) s += wrow[d] * arow[d];
      val = s;
    }
    unsigned short hu = f2b_rne(val);
    float lof = val - us2f(hu);
    Bp2[((size_t)(ks * 5) + f) * 512 + lane * 8 + j]        = (short)hu;
    Bp2[((size_t)((16 + ks) * 5) + f) * 512 + lane * 8 + j] = (short)f2b_rne(lof);
  }
}

// MLP1: B = W1 : 64 x 640, 40 frags, 2 ks
__global__ void k_prep3(const float* __restrict__ W1, short* __restrict__ Bp3){
  int f = blockIdx.x >> 1, ks = blockIdx.x & 1;
  int lane = threadIdx.x;
  int kg = lane >> 4, cl = lane & 15;
  int col = f * 16 + cl;
  for (int j = 0; j < 8; j++){
    int k = ks * 32 + kg * 8 + j;
    float val = W1[(size_t)k * 640 + col];
    unsigned short hu = f2b_rne(val);
    float lof = val - us2f(hu);
    Bp3[((size_t)(ks * 40) + f) * 512 + lane * 8 + j]       = (short)hu;
    Bp3[((size_t)((2 + ks) * 40) + f) * 512 + lane * 8 + j] = (short)f2b_rne(lof);
  }
}

// ---------- GEMM1 via MFMA: H = x @ Wcat (alpha folded as extra cols) ----------
// H stored as fp8 e4m3 (512 B/row) -> halves agg1 gather traffic.
__global__ void __launch_bounds__(256)
k_gemm1_mfma(const float* __restrict__ x, const short* __restrict__ Bp1,
             unsigned char* __restrict__ Hb8, float* __restrict__ a1s,
             float* __restrict__ a1d, int n_nodes){
  __shared__ short xsh[16][72];   // hi bf16
  __shared__ short xsl[16][72];   // lo bf16
  __shared__ short Ht[16][520];   // output transpose buffer (bf16) for coalesced write
  int n0 = blockIdx.x * 16;
  int t = threadIdx.x;
  for (int i = t; i < 16 * 64; i += 256){
    int r = i >> 6, c = i & 63;
    int nn = n0 + r;
    float v = (nn < n_nodes) ? x[(size_t)nn * NF + c] : 0.f;
    unsigned short hu = f2b_rne(v);
    float lof = v - us2f(hu);
    xsh[r][c] = (short)hu;
    xsl[r][c] = (short)f2b_rne(lof);
  }
  __syncthreads();
  int wid = t >> 6, lane = t & 63;
  int rowa = lane & 15, kg = lane >> 4, cl = lane & 15;
  short8 ah[2], al[2];
  #pragma unroll
  for (int ks = 0; ks < 2; ks++){
    ah[ks] = *reinterpret_cast<const short8*>(&xsh[rowa][ks * 32 + kg * 8]);
    al[ks] = *reinterpret_cast<const short8*>(&xsl[rowa][ks * 32 + kg * 8]);
  }
  int nf = (wid == 3) ? 9 : 8;          // wave 3 also does the alpha frag (f=32)
  for (int f0 = 0; f0 < nf; f0++){
    int f = wid * 8 + f0;
    f32x4 acc = {0.f, 0.f, 0.f, 0.f};
    #pragma unroll
    for (int ks = 0; ks < 2; ks++){
      short8 b_h = *reinterpret_cast<const short8*>(Bp1 + ((size_t)(ks * 33) + f) * 512 + lane * 8);
      short8 b_l = *reinterpret_cast<const short8*>(Bp1 + ((size_t)((2 + ks) * 33) + f) * 512 + lane * 8);
      acc = mfma16(ah[ks], b_h, acc);   // hi*hi
      acc = mfma16(al[ks], b_h, acc);   // lo*hi
      acc = mfma16(ah[ks], b_l, acc);   // hi*lo
    }
    if (f < 32){
      #pragma unroll
      for (int reg = 0; reg < 4; reg++)
        Ht[kg * 4 + reg][f * 16 + cl] = (short)f2b_rne(acc[reg]);
    } else {
      #pragma unroll
      for (int reg = 0; reg < 4; reg++){
        int nn = n0 + kg * 4 + reg;
        if (nn < n_nodes){
          if (cl < 8) a1s[nn * NH + cl] = acc[reg];
          else        a1d[nn * NH + (cl - 8)] = acc[reg];
        }
      }
    }
  }
  __syncthreads();
  // fp8-pack copy-out: 8 adjacent cols per thread-iter -> 8 bytes
  for (int i = t; i < 16 * 64; i += 256){
    int r = i >> 6, c8 = (i & 63) * 8;
    int nn = n0 + r;
    if (nn < n_nodes){
      short8 hv = *reinterpret_cast<const short8*>(&Ht[r][c8]);
      unsigned int w0, w1;
      w0 = __builtin_amdgcn_cvt_pk_fp8_f32(us2f((unsigned short)hv[0]), us2f((unsigned short)hv[1]), 0, false);
      w0 = __builtin_amdgcn_cvt_pk_fp8_f32(us2f((unsigned short)hv[2]), us2f((unsigned short)hv[3]), w0, true);
      w1 = __builtin_amdgcn_cvt_pk_fp8_f32(us2f((unsigned short)hv[4]), us2f((unsigned short)hv[5]), 0, false);
      w1 = __builtin_amdgcn_cvt_pk_fp8_f32(us2f((unsigned short)hv[6]), us2f((unsigned short)hv[7]), w1, true);
      u32x2 w; w.x = w0; w.y = w1;
      *reinterpret_cast<u32x2*>(Hb8 + (size_t)nn * 512 + c8) = w;
    }
  }
}

// ---------- CSR build ----------
__global__ void k_count(const int* __restrict__ row, int* __restrict__ cnt, int E){
  int e = blockIdx.x * blockDim.x + threadIdx.x;
  if (e < E) atomicAdd(&cnt[row[e]], 1);
}

__global__ void k_scan_a(const int* __restrict__ cnt, int* __restrict__ incl,
                         int* __restrict__ bsum, int n){
  __shared__ int s[1024];
  int i = blockIdx.x * 1024 + threadIdx.x;
  int v = (i < n) ? cnt[i] : 0;
  s[threadIdx.x] = v;
  __syncthreads();
  for (int d = 1; d < 1024; d <<= 1){
    int tv = (threadIdx.x >= d) ? s[threadIdx.x - d] : 0;
    __syncthreads();
    s[threadIdx.x] += tv;
    __syncthreads();
  }
  if (i < n) incl[i] = s[threadIdx.x];
  if (threadIdx.x == 1023) bsum[blockIdx.x] = s[1023];
}

__global__ void k_scan_b(const int* __restrict__ bsum, int* __restrict__ boff, int nb){
  __shared__ int s[128];
  int t = threadIdx.x;
  if (nb <= 128){
    int v = (t < nb) ? bsum[t] : 0;
    s[t] = v;
    __syncthreads();
    for (int d = 1; d < 128; d <<= 1){
      int tv = (t >= d) ? s[t - d] : 0;
      __syncthreads();
      s[t] += tv;
      __syncthreads();
    }
    if (t < nb) boff[t] = s[t] - v;   // exclusive
  } else if (t == 0){
    int run = 0;
    for (int b = 0; b < nb; b++){ boff[b] = run; run += bsum[b]; }
  }
}

__global__ void k_scan_c(const int* __restrict__ incl, const int* __restrict__ cnt,
                         const int* __restrict__ boff, int* __restrict__ rowptr,
                         int* __restrict__ wptr, int n){
  int i = blockIdx.x * 1024 + threadIdx.x;
  if (i < n){
    int start = incl[i] - cnt[i] + boff[blockIdx.x];
    rowptr[i] = start;
    wptr[i]   = start;
  }
}

__global__ void k_scatter(const int* __restrict__ row, const int* __restrict__ col,
                          int* __restrict__ wptr, int* __restrict__ scol, int E){
  int e = blockIdx.x * blockDim.x + threadIdx.x;
  if (e < E){
    int r = row[e];
    int pos = atomicAdd(&wptr[r], 1);
    scol[pos] = col[e];
  }
}

// ---------- sort each CSR row's columns (wave bitonic, <=64 elems) ----------
__global__ void k_sortrows(const int* __restrict__ rowptr, const int* __restrict__ cnt,
                           int* __restrict__ scol, int n_nodes){
  int n = blockIdx.x * 4 + (threadIdx.x >> 6);
  int lane = threadIdx.x & 63;
  if (n >= n_nodes) return;
  int c = cnt[n];
  if (c < 2 || c > 64) return;
  int beg = rowptr[n];
  int v = (lane < c) ? scol[beg + lane] : 0x7FFFFFFF;
  #pragma unroll
  for (int k = 2; k <= 64; k <<= 1){
    #pragma unroll
    for (int j = k >> 1; j > 0; j >>= 1){
      int o = __shfl_xor(v, j);
      bool dirUp = ((lane & k) == 0);
      bool takeMin = (((lane & j) == 0) == dirUp);
      int mn = (v < o) ? v : o;
      int mx = (v < o) ? o : v;
      v = takeMin ? mn : mx;
    }
  }
  if (lane < c) scol[beg + lane] = v;
}

// ---------- fused agg1 + MFMA GEMM2 (alpha2 folded as 2 extra cols) ----------
// 8 nodes/block, 512 threads (8 waves). Round-3 loop structure (compiler
// software-pipelines the 4 independent gathers); fp8 rows decoded with
// v_cvt_pk_f32_fp8 (1 op -> 2 floats).
__global__ void __launch_bounds__(512, 2)
k_agg1_gemm2(const unsigned char* __restrict__ Hb8, const float* __restrict__ a1s,
             const float* __restrict__ a1d, const int* __restrict__ rowptr,
             const int* __restrict__ cnt, const int* __restrict__ scol,
             const short* __restrict__ Bp2, bf16* __restrict__ h2b,
             float* __restrict__ a2s, float* __restrict__ a2d, int n_nodes){
  __shared__ short xh[8][528];   // elu(h_prime) hi bf16
  __shared__ short xl[8][528];   // lo bf16
  int n0   = blockIdx.x * 8;
  int wid  = threadIdx.x >> 6;
  int lane = threadIdx.x & 63;
  int hsel = lane >> 3;
  int n = n0 + wid;

  if (n < n_nodes){
    float asrc = a1s[n * NH + hsel];
    int beg = rowptr[n], endk = beg + cnt[n];
    f32x2 acc2[4] = {{0.f,0.f},{0.f,0.f},{0.f,0.f},{0.f,0.f}};
    float rsum = 0.f;
    int k = beg;
    for (; k + 3 < endk; k += 4){
      int c0 = scol[k], c1 = scol[k + 1], c2 = scol[k + 2], c3 = scol[k + 3];
      u32x2 q0 = *reinterpret_cast<const u32x2*>(Hb8 + (size_t)c0 * 512 + lane * 8);
      u32x2 q1 = *reinterpret_cast<const u32x2*>(Hb8 + (size_t)c1 * 512 + lane * 8);
      u32x2 q2 = *reinterpret_cast<const u32x2*>(Hb8 + (size_t)c2 * 512 + lane * 8);
      u32x2 q3 = *reinterpret_cast<const u32x2*>(Hb8 + (size_t)c3 * 512 + lane * 8);
      float s0 = asrc + a1d[c0 * NH + hsel];
      float s1 = asrc + a1d[c1 * NH + hsel];
      float s2 = asrc + a1d[c2 * NH + hsel];
      float s3 = asrc + a1d[c3 * NH + hsel];
      float l0 = fmaxf(s0, SLOPE * s0);
      float l1 = fmaxf(s1, SLOPE * s1);
      float l2 = fmaxf(s2, SLOPE * s2);
      float l3 = fmaxf(s3, SLOPE * s3);
      float e0 = __expf(-l0);
      float e1 = __expf(-l1);
      float e2 = __expf(-l2);
      float e3 = __expf(-l3);
      rsum += (e0 + e1) + (e2 + e3);
      f32x2 ev0 = {e0, e0}, ev1 = {e1, e1}, ev2 = {e2, e2}, ev3 = {e3, e3};
      acc2[0] += ev0 * __builtin_amdgcn_cvt_pk_f32_fp8(q0.x, false);
      acc2[1] += ev0 * __builtin_amdgcn_cvt_pk_f32_fp8(q0.x, true);
      acc2[2] += ev0 * __builtin_amdgcn_cvt_pk_f32_fp8(q0.y, false);
      acc2[3] += ev0 * __builtin_amdgcn_cvt_pk_f32_fp8(q0.y, true);
      acc2[0] += ev1 * __builtin_amdgcn_cvt_pk_f32_fp8(q1.x, false);
      acc2[1] += ev1 * __builtin_amdgcn_cvt_pk_f32_fp8(q1.x, true);
      acc2[2] += ev1 * __builtin_amdgcn_cvt_pk_f32_fp8(q1.y, false);
      acc2[3] += ev1 * __builtin_amdgcn_cvt_pk_f32_fp8(q1.y, true);
      acc2[0] += ev2 * __builtin_amdgcn_cvt_pk_f32_fp8(q2.x, false);
      acc2[1] += ev2 * __builtin_amdgcn_cvt_pk_f32_fp8(q2.x, true);
      acc2[2] += ev2 * __builtin_amdgcn_cvt_pk_f32_fp8(q2.y, false);
      acc2[3] += ev2 * __builtin_amdgcn_cvt_pk_f32_fp8(q2.y, true);
      acc2[0] += ev3 * __builtin_amdgcn_cvt_pk_f32_fp8(q3.x, false);
      acc2[1] += ev3 * __builtin_amdgcn_cvt_pk_f32_fp8(q3.x, true);
      acc2[2] += ev3 * __builtin_amdgcn_cvt_pk_f32_fp8(q3.y, false);
      acc2[3] += ev3 * __builtin_amdgcn_cvt_pk_f32_fp8(q3.y, true);
    }
    for (; k < endk; ++k){
      int c0 = scol[k];
      u32x2 q0 = *reinterpret_cast<const u32x2*>(Hb8 + (size_t)c0 * 512 + lane * 8);
      float s0 = asrc + a1d[c0 * NH + hsel];
      float l0 = fmaxf(s0, SLOPE * s0);
      float e0 = __expf(-l0);
      rsum += e0;
      f32x2 ev0 = {e0, e0};
      acc2[0] += ev0 * __builtin_amdgcn_cvt_pk_f32_fp8(q0.x, false);
      acc2[1] += ev0 * __builtin_amdgcn_cvt_pk_f32_fp8(q0.x, true);
      acc2[2] += ev0 * __builtin_amdgcn_cvt_pk_f32_fp8(q0.y, false);
      acc2[3] += ev0 * __builtin_amdgcn_cvt_pk_f32_fp8(q0.y, true);
    }
    float inv = 1.f / rsum;
    short8 hv8, lv8;
    #pragma unroll
    for (int jj = 0; jj < 8; jj++){
      float v = acc2[jj >> 1][jj & 1] * inv;
      v = (v > 0.f) ? v : (__expf(v) - 1.f);   // elu
      unsigned short hu = f2b_rne(v);
      float lof = v - us2f(hu);
      hv8[jj] = (short)hu;
      lv8[jj] = (short)f2b_rne(lof);
    }
    *reinterpret_cast<short8*>(&xh[wid][lane * 8]) = hv8;
    *reinterpret_cast<short8*>(&xl[wid][lane * 8]) = lv8;
  } else {
    short8 z = {0,0,0,0,0,0,0,0};
    *reinterpret_cast<short8*>(&xh[wid][lane * 8]) = z;
    *reinterpret_cast<short8*>(&xl[wid][lane * 8]) = z;
  }
  __syncthreads();

  // ---- phase 2+3: MFMA GEMM2; waves 0-3 -> h2b cols, wave 4 -> alpha2 ----
  if (wid < 5){
    int rowa = lane & 7;            // A rows 8-15 duplicate 0-7 (outputs discarded)
    int kg   = lane >> 4;
    f32x4 acc = {0.f, 0.f, 0.f, 0.f};
    #pragma unroll 4
    for (int ks = 0; ks < 16; ks++){
      short8 a_h = *reinterpret_cast<const short8*>(&xh[rowa][ks * 32 + kg * 8]);
      short8 a_l = *reinterpret_cast<const short8*>(&xl[rowa][ks * 32 + kg * 8]);
      short8 b_h = *reinterpret_cast<const short8*>(Bp2 + ((size_t)(ks * 5) + wid) * 512 + lane * 8);
      short8 b_l = *reinterpret_cast<const short8*>(Bp2 + ((size_t)((16 + ks) * 5) + wid) * 512 + lane * 8);
      acc = mfma16(a_h, b_h, acc);
      acc = mfma16(a_l, b_h, acc);
      acc = mfma16(a_h, b_l, acc);
    }
    int cl = lane & 15;
    if (kg < 2){                    // D rows 0-7 = our 8 nodes
      #pragma unroll
      for (int reg = 0; reg < 4; reg++){
        int nn = n0 + kg * 4 + reg;
        if (nn < n_nodes){
          if (wid < 4){
            h2b[(size_t)nn * 64 + wid * 16 + cl] = f2b(acc[reg]);
          } else if (cl == 0){
            a2s[nn] = acc[reg];
          } else if (cl == 1){
            a2d[nn] = acc[reg];
          }
        }
      }
    }
  }
}

// ---------- aggregation layer 2: one wave per node, 4-edge unroll ----------
__global__ void k_agg2(const bf16* __restrict__ h2b, const float* __restrict__ a2s,
                       const float* __restrict__ a2d, const int* __restrict__ rowptr,
                       const int* __restrict__ cnt, const int* __restrict__ scol,
                       float* __restrict__ xo, int n_nodes){
  int n = blockIdx.x * 4 + (threadIdx.x >> 6);
  int lane = threadIdx.x & 63;
  if (n >= n_nodes) return;
  float asrc = a2s[n];
  int beg = rowptr[n], endk = beg + cnt[n];
  float acc = 0.f, rsum = 0.f;
  int k = beg;
  for (; k + 3 < endk; k += 4){
    int c0 = scol[k], c1 = scol[k + 1], c2 = scol[k + 2], c3 = scol[k + 3];
    float v0 = b2f(h2b[(size_t)c0 * 64 + lane]);
    float v1 = b2f(h2b[(size_t)c1 * 64 + lane]);
    float v2 = b2f(h2b[(size_t)c2 * 64 + lane]);
    float v3 = b2f(h2b[(size_t)c3 * 64 + lane]);
    float s0 = asrc + a2d[c0];
    float s1 = asrc + a2d[c1];
    float s2 = asrc + a2d[c2];
    float s3 = asrc + a2d[c3];
    float l0 = fmaxf(s0, SLOPE * s0);
    float l1 = fmaxf(s1, SLOPE * s1);
    float l2 = fmaxf(s2, SLOPE * s2);
    float l3 = fmaxf(s3, SLOPE * s3);
    float e0 = __expf(-l0);
    float e1 = __expf(-l1);
    float e2 = __expf(-l2);
    float e3 = __expf(-l3);
    rsum += (e0 + e1) + (e2 + e3);
    acc  += (e0 * v0 + e1 * v1) + (e2 * v2 + e3 * v3);
  }
  for (; k < endk; ++k){
    int c0 = scol[k];
    float v0 = b2f(h2b[(size_t)c0 * 64 + lane]);
    float s0 = asrc + a2d[c0];
    float l0 = fmaxf(s0, SLOPE * s0);
    float e0 = __expf(-l0);
    rsum += e0;
    acc  += e0 * v0;
  }
  float v = acc / rsum;
  v = (v > 0.f) ? v : (__expf(v) - 1.f);         // elu applied after layer 2
  xo[(size_t)n * 64 + lane] = v;
}

// ---------- MLP head: MFMA for W1 stage, 16 nodes/block ----------
__global__ void __launch_bounds__(256)
k_mlp(const float* __restrict__ xo, const short* __restrict__ Bp3,
      const float* __restrict__ b1, const float* __restrict__ W2,
      const float* __restrict__ b2, const float* __restrict__ W3,
      const float* __restrict__ b3, float* __restrict__ out, int n_nodes){
  __shared__ short xsh[16][72];
  __shared__ short xsl[16][72];
  __shared__ float z1[16][650];   // 650: conflict-free kg groups
  __shared__ float z2[16][10];
  int n0 = blockIdx.x * 16;
  int t  = threadIdx.x;
  for (int i = t; i < 16 * 64; i += 256){
    int r = i >> 6, c = i & 63;
    int nn = n0 + r;
    float v = (nn < n_nodes) ? xo[(size_t)nn * 64 + c] : 0.f;
    unsigned short hu = f2b_rne(v);
    float lof = v - us2f(hu);
    xsh[r][c] = (short)hu;
    xsl[r][c] = (short)f2b_rne(lof);
  }
  __syncthreads();
  int wid = t >> 6, lane = t & 63;
  int rowa = lane & 15, kg = lane >> 4, cl = lane & 15;
  short8 ah[2], al[2];
  #pragma unroll
  for (int ks = 0; ks < 2; ks++){
    ah[ks] = *reinterpret_cast<const short8*>(&xsh[rowa][ks * 32 + kg * 8]);
    al[ks] = *reinterpret_cast<const short8*>(&xsl[rowa][ks * 32 + kg * 8]);
  }
  for (int f0 = 0; f0 < 10; f0++){
    int f = wid * 10 + f0;
    f32x4 acc = {0.f, 0.f, 0.f, 0.f};
    #pragma unroll
    for (int ks = 0; ks < 2; ks++){
      short8 b_h = *reinterpret_cast<const short8*>(Bp3 + ((size_t)(ks * 40) + f) * 512 + lane * 8);
      short8 b_l = *reinterpret_cast<const short8*>(Bp3 + ((size_t)((2 + ks) * 40) + f) * 512 + lane * 8);
      acc = mfma16(ah[ks], b_h, acc);
      acc = mfma16(al[ks], b_h, acc);
      acc = mfma16(ah[ks], b_l, acc);
    }
    int cc = f * 16 + cl;
    float bb = b1[cc];
    #pragma unroll
    for (int reg = 0; reg < 4; reg++)
      z1[kg * 4 + reg][cc] = fmaxf(acc[reg] + bb, 0.f);
  }
  __syncthreads();
  {
    int g = t >> 4, sub = t & 15;
    float p[10];
    #pragma unroll
    for (int kk = 0; kk < 10; kk++) p[kk] = 0.f;
    for (int jj = 0; jj < 40; jj++){
      int j = sub + jj * 16;
      float v = z1[g][j];
      #pragma unroll
      for (int kk = 0; kk < 10; kk++) p[kk] += v * W2[j * 10 + kk];
    }
    #pragma unroll
    for (int kk = 0; kk < 10; kk++){
      #pragma unroll
      for (int m = 8; m; m >>= 1) p[kk] += __shfl_xor(p[kk], m);
    }
    if (sub == 0){
      #pragma unroll
      for (int kk = 0; kk < 10; kk++) z2[g][kk] = fmaxf(p[kk] + b2[kk], 0.f);
    }
  }
  __syncthreads();
  if (t < 16){
    int nn = n0 + t;
    if (nn < n_nodes){
      float acc = b3[0];
      #pragma unroll
      for (int kk = 0; kk < 10; kk++) acc += z2[t][kk] * W3[kk];
      out[nn] = 1.f / (1.f + __expf(-acc));
    }
  }
}

extern "C" void kernel_launch(void* const* d_in, const int* in_sizes, int n_in,
                              void* d_out, int out_size, void* d_ws, size_t ws_size,
                              hipStream_t stream){
  const float* x    = (const float*)d_in[0];
  const int*   ei   = (const int*)  d_in[1];
  const float* Watt = (const float*)d_in[2];
  const float* aatt = (const float*)d_in[3];
  const float* Wout = (const float*)d_in[4];
  const float* aout = (const float*)d_in[5];
  const float* W1   = (const float*)d_in[6];
  const float* b1   = (const float*)d_in[7];
  const float* W2   = (const float*)d_in[8];
  const float* b2   = (const float*)d_in[9];
  const float* W3   = (const float*)d_in[10];
  const float* b3   = (const float*)d_in[11];
  float* out = (float*)d_out;

  int N = in_sizes[0] / NF;
  int E = in_sizes[1] / 2;
  const int* row = ei;
  const int* col = ei + E;

  char* base = (char*)d_ws;
  size_t off = 0;
  auto alloc = [&](size_t bytes) -> void* {
    void* p = base + off;
    off = (off + bytes + 255) & ~(size_t)255;
    return p;
  };
  unsigned char* Hb8 = (unsigned char*)alloc((size_t)N * 512);   // 51.2 MB fp8
  bf16*  h2b    = (bf16*) alloc((size_t)N * 64 * 2);   // 12.8 MB
  float* xo     = (float*)alloc((size_t)N * 64 * 4);   // 25.6 MB
  float* a1s    = (float*)alloc((size_t)N * NH * 4);
  float* a1d    = (float*)alloc((size_t)N * NH * 4);
  float* a2s    = (float*)alloc((size_t)N * 4);
  float* a2d    = (float*)alloc((size_t)N * 4);
  int*   cnt    = (int*)  alloc((size_t)N * 4);
  int*   rowptr = (int*)  alloc((size_t)N * 4);
  int*   wptr   = (int*)  alloc((size_t)N * 4);
  int*   incl   = (int*)  alloc((size_t)N * 4);
  int    NB     = (N + 1023) / 1024;
  int*   bsum   = (int*)  alloc((size_t)NB * 4);
  int*   boff   = (int*)  alloc((size_t)NB * 4);
  int*   scol   = (int*)  alloc((size_t)E * 4);        // 6.4 MB
  short* Bp1    = (short*)alloc((size_t)4 * 33 * 512 * 2);   // 135 KB packed W_att|alpha1
  short* Bp2    = (short*)alloc((size_t)32 * 5 * 512 * 2);   // 160 KB packed Wout|alpha2
  short* Bp3    = (short*)alloc((size_t)4 * 40 * 512 * 2);   // 160 KB packed W1
  (void)ws_size; (void)n_in; (void)out_size;

  hipMemsetAsync(cnt, 0, (size_t)N * 4, stream);

  k_prep1     <<<66,              64, 0, stream>>>(Watt, aatt, Bp1);
  k_prep2     <<<80,              64, 0, stream>>>(Wout, aout, Bp2);
  k_prep3     <<<80,              64, 0, stream>>>(W1, Bp3);
  k_gemm1_mfma<<<(N + 15) / 16,  256, 0, stream>>>(x, Bp1, Hb8, a1s, a1d, N);
  k_count     <<<(E + 255) / 256, 256, 0, stream>>>(row, cnt, E);
  k_scan_a    <<<NB,             1024, 0, stream>>>(cnt, incl, bsum, N);
  k_scan_b    <<<1,               128, 0, stream>>>(bsum, boff, NB);
  k_scan_c    <<<NB,             1024, 0, stream>>>(incl, cnt, boff, rowptr, wptr, N);
  k_scatter   <<<(E + 255) / 256, 256, 0, stream>>>(row, col, wptr, scol, E);
  k_sortrows  <<<(N + 3) / 4,     256, 0, stream>>>(rowptr, cnt, scol, N);
  k_agg1_gemm2<<<(N + 7) / 8,     512, 0, stream>>>(Hb8, a1s, a1d, rowptr, cnt, scol,
                                                    Bp2, h2b, a2s, a2d, N);
  k_agg2      <<<(N + 3) / 4,     256, 0, stream>>>(h2b, a2s, a2d, rowptr, cnt, scol, xo, N);
  k_mlp       <<<(N + 15) / 16,  256, 0, stream>>>(xo, Bp3, b1, W2, b2, W3, b3, out, N);
}

// Round 6
// 710.581 us; speedup vs baseline: 1.1689x; 1.0545x over previous
//
#include <hip/hip_runtime.h>
#include <hip/hip_bf16.h>
#include <math.h>

#define NF 64
#define NH 8
#define HD 512   // NH * 64 (logical H width; stored as fp8 bytes)
#define SLOPE 0.2f

typedef __hip_bfloat16 bf16;
typedef short short8 __attribute__((ext_vector_type(8)));
typedef unsigned int u32x2 __attribute__((ext_vector_type(2)));
typedef unsigned int uint4v __attribute__((ext_vector_type(4)));
typedef float f32x4 __attribute__((ext_vector_type(4)));
typedef float f32x2 __attribute__((ext_vector_type(2)));

__device__ __forceinline__ float b2f(bf16 v){ return __bfloat162float(v); }
__device__ __forceinline__ bf16 f2b(float v){ return __float2bfloat16(v); }
__device__ __forceinline__ float us2f(unsigned short u){
  union{ unsigned int i; float f; } c; c.i = ((unsigned int)u) << 16; return c.f;
}
// unpack packed 2xbf16 dword -> f32 (low / high element)
__device__ __forceinline__ float lo16(unsigned int u){
  union{ unsigned int i; float f; } c; c.i = u << 16; return c.f;
}
__device__ __forceinline__ float hi16(unsigned int u){
  union{ unsigned int i; float f; } c; c.i = u & 0xFFFF0000u; return c.f;
}
// round-to-nearest-even f32 -> bf16 bits
__device__ __forceinline__ unsigned short f2b_rne(float v){
  union{ float f; unsigned int i; } c; c.f = v;
  unsigned int b = c.i + 0x7FFF + ((c.i >> 16) & 1);
  return (unsigned short)(b >> 16);
}
__device__ __forceinline__ f32x4 mfma16(short8 a, short8 b, f32x4 c){
  return __builtin_amdgcn_mfma_f32_16x16x32_bf16(a, b, c, 0, 0, 0);
}

// ---------- weight pre-pack kernels (tiny, run once per launch) ----------
// B-fragment layout for mfma_f32_16x16x32_bf16: b[j] = B[(lane>>4)*8+j][lane&15]
// Packed as [term(hi=0,lo=1)][ks][frag][lane][j] -> coalesced short8 per lane.

// GEMM1: B = [W_att heads (512 cols) | W@a_src (8) | W@a_dst (8)] : 64 x 528, 33 frags, 2 ks
__global__ void k_prep1(const float* __restrict__ Watt, const float* __restrict__ aatt,
                        short* __restrict__ Bp1){
  int f = blockIdx.x >> 1, ks = blockIdx.x & 1;
  int lane = threadIdx.x;
  int kg = lane >> 4, cl = lane & 15;
  int col = f * 16 + cl;
  for (int j = 0; j < 8; j++){
    int k = ks * 32 + kg * 8 + j;
    float val;
    if (col < 512){
      val = Watt[(size_t)(col >> 6) * 4096 + k * 64 + (col & 63)];
    } else {
      int h = (col - 512) & 7;
      const float* arow = aatt + h * 128 + ((col >= 520) ? 64 : 0);
      const float* wrow = Watt + (size_t)h * 4096 + k * 64;
      float s = 0.f;
      for (int d = 0; d < 64; d++) s += wrow[d] * arow[d];
      val = s;
    }
    unsigned short hu = f2b_rne(val);
    float lof = val - us2f(hu);
    Bp1[((size_t)(ks * 33) + f) * 512 + lane * 8 + j]       = (short)hu;
    Bp1[((size_t)((2 + ks) * 33) + f) * 512 + lane * 8 + j] = (short)f2b_rne(lof);
  }
}

// GEMM2: B = [Wout (64 cols) | Wout@aout_s | Wout@aout_d | pad] : 512 x 80, 5 frags, 16 ks
__global__ void k_prep2(const float* __restrict__ Wout, const float* __restrict__ aout,
                        short* __restrict__ Bp2){
  int f = blockIdx.x >> 4, ks = blockIdx.x & 15;
  int lane = threadIdx.x;
  int kg = lane >> 4, cl = lane & 15;
  int col = f * 16 + cl;
  for (int j = 0; j < 8; j++){
    int k = ks * 32 + kg * 8 + j;
    float val = 0.f;
    if (col < 64){
      val = Wout[(size_t)k * 64 + col];
    } else if (col == 64 || col == 65){
      const float* arow = aout + ((col == 65) ? 64 : 0);
      const float* wrow = Wout + (size_t)k * 64;
      float s = 0.f;
      for (int d = 0; d < 64; d++) s += wrow[d] * arow[d];
      val = s;
    }
    unsigned short hu = f2b_rne(val);
    float lof = val - us2f(hu);
    Bp2[((size_t)(ks * 5) + f) * 512 + lane * 8 + j]        = (short)hu;
    Bp2[((size_t)((16 + ks) * 5) + f) * 512 + lane * 8 + j] = (short)f2b_rne(lof);
  }
}

// MLP1: B = W1 : 64 x 640, 40 frags, 2 ks
__global__ void k_prep3(const float* __restrict__ W1, short* __restrict__ Bp3){
  int f = blockIdx.x >> 1, ks = blockIdx.x & 1;
  int lane = threadIdx.x;
  int kg = lane >> 4, cl = lane & 15;
  int col = f * 16 + cl;
  for (int j = 0; j < 8; j++){
    int k = ks * 32 + kg * 8 + j;
    float val = W1[(size_t)k * 640 + col];
    unsigned short hu = f2b_rne(val);
    float lof = val - us2f(hu);
    Bp3[((size_t)(ks * 40) + f) * 512 + lane * 8 + j]       = (short)hu;
    Bp3[((size_t)((2 + ks) * 40) + f) * 512 + lane * 8 + j] = (short)f2b_rne(lof);
  }
}

// ---------- GEMM1 via MFMA: H = x @ Wcat (alpha folded as extra cols) ----------
// H stored as fp8 e4m3 (512 B/row) -> halves agg1 gather traffic.
__global__ void __launch_bounds__(256)
k_gemm1_mfma(const float* __restrict__ x, const short* __restrict__ Bp1,
             unsigned char* __restrict__ Hb8, float* __restrict__ a1s,
             float* __restrict__ a1d, int n_nodes){
  __shared__ short xsh[16][72];   // hi bf16
  __shared__ short xsl[16][72];   // lo bf16
  __shared__ short Ht[16][520];   // output transpose buffer (bf16) for coalesced write
  int n0 = blockIdx.x * 16;
  int t = threadIdx.x;
  for (int i = t; i < 16 * 64; i += 256){
    int r = i >> 6, c = i & 63;
    int nn = n0 + r;
    float v = (nn < n_nodes) ? x[(size_t)nn * NF + c] : 0.f;
    unsigned short hu = f2b_rne(v);
    float lof = v - us2f(hu);
    xsh[r][c] = (short)hu;
    xsl[r][c] = (short)f2b_rne(lof);
  }
  __syncthreads();
  int wid = t >> 6, lane = t & 63;
  int rowa = lane & 15, kg = lane >> 4, cl = lane & 15;
  short8 ah[2], al[2];
  #pragma unroll
  for (int ks = 0; ks < 2; ks++){
    ah[ks] = *reinterpret_cast<const short8*>(&xsh[rowa][ks * 32 + kg * 8]);
    al[ks] = *reinterpret_cast<const short8*>(&xsl[rowa][ks * 32 + kg * 8]);
  }
  int nf = (wid == 3) ? 9 : 8;          // wave 3 also does the alpha frag (f=32)
  for (int f0 = 0; f0 < nf; f0++){
    int f = wid * 8 + f0;
    f32x4 acc = {0.f, 0.f, 0.f, 0.f};
    #pragma unroll
    for (int ks = 0; ks < 2; ks++){
      short8 b_h = *reinterpret_cast<const short8*>(Bp1 + ((size_t)(ks * 33) + f) * 512 + lane * 8);
      short8 b_l = *reinterpret_cast<const short8*>(Bp1 + ((size_t)((2 + ks) * 33) + f) * 512 + lane * 8);
      acc = mfma16(ah[ks], b_h, acc);   // hi*hi
      acc = mfma16(al[ks], b_h, acc);   // lo*hi
      acc = mfma16(ah[ks], b_l, acc);   // hi*lo
    }
    if (f < 32){
      #pragma unroll
      for (int reg = 0; reg < 4; reg++)
        Ht[kg * 4 + reg][f * 16 + cl] = (short)f2b_rne(acc[reg]);
    } else {
      #pragma unroll
      for (int reg = 0; reg < 4; reg++){
        int nn = n0 + kg * 4 + reg;
        if (nn < n_nodes){
          if (cl < 8) a1s[nn * NH + cl] = acc[reg];
          else        a1d[nn * NH + (cl - 8)] = acc[reg];
        }
      }
    }
  }
  __syncthreads();
  // fp8-pack copy-out: 8 adjacent cols per thread-iter -> 8 bytes
  for (int i = t; i < 16 * 64; i += 256){
    int r = i >> 6, c8 = (i & 63) * 8;
    int nn = n0 + r;
    if (nn < n_nodes){
      short8 hv = *reinterpret_cast<const short8*>(&Ht[r][c8]);
      unsigned int w0, w1;
      w0 = __builtin_amdgcn_cvt_pk_fp8_f32(us2f((unsigned short)hv[0]), us2f((unsigned short)hv[1]), 0, false);
      w0 = __builtin_amdgcn_cvt_pk_fp8_f32(us2f((unsigned short)hv[2]), us2f((unsigned short)hv[3]), w0, true);
      w1 = __builtin_amdgcn_cvt_pk_fp8_f32(us2f((unsigned short)hv[4]), us2f((unsigned short)hv[5]), 0, false);
      w1 = __builtin_amdgcn_cvt_pk_fp8_f32(us2f((unsigned short)hv[6]), us2f((unsigned short)hv[7]), w1, true);
      u32x2 w; w.x = w0; w.y = w1;
      *reinterpret_cast<u32x2*>(Hb8 + (size_t)nn * 512 + c8) = w;
    }
  }
}

// ---------- CSR build ----------
__global__ void k_count(const int* __restrict__ row, int* __restrict__ cnt, int E){
  int e = blockIdx.x * blockDim.x + threadIdx.x;
  if (e < E) atomicAdd(&cnt[row[e]], 1);
}

__global__ void k_scan_a(const int* __restrict__ cnt, int* __restrict__ incl,
                         int* __restrict__ bsum, int n){
  __shared__ int s[1024];
  int i = blockIdx.x * 1024 + threadIdx.x;
  int v = (i < n) ? cnt[i] : 0;
  s[threadIdx.x] = v;
  __syncthreads();
  for (int d = 1; d < 1024; d <<= 1){
    int tv = (threadIdx.x >= d) ? s[threadIdx.x - d] : 0;
    __syncthreads();
    s[threadIdx.x] += tv;
    __syncthreads();
  }
  if (i < n) incl[i] = s[threadIdx.x];
  if (threadIdx.x == 1023) bsum[blockIdx.x] = s[1023];
}

__global__ void k_scan_b(const int* __restrict__ bsum, int* __restrict__ boff, int nb){
  __shared__ int s[128];
  int t = threadIdx.x;
  if (nb <= 128){
    int v = (t < nb) ? bsum[t] : 0;
    s[t] = v;
    __syncthreads();
    for (int d = 1; d < 128; d <<= 1){
      int tv = (t >= d) ? s[t - d] : 0;
      __syncthreads();
      s[t] += tv;
      __syncthreads();
    }
    if (t < nb) boff[t] = s[t] - v;   // exclusive
  } else if (t == 0){
    int run = 0;
    for (int b = 0; b < nb; b++){ boff[b] = run; run += bsum[b]; }
  }
}

__global__ void k_scan_c(const int* __restrict__ incl, const int* __restrict__ cnt,
                         const int* __restrict__ boff, int* __restrict__ rowptr,
                         int* __restrict__ wptr, int n){
  int i = blockIdx.x * 1024 + threadIdx.x;
  if (i < n){
    int start = incl[i] - cnt[i] + boff[blockIdx.x];
    rowptr[i] = start;
    wptr[i]   = start;
  }
}

__global__ void k_scatter(const int* __restrict__ row, const int* __restrict__ col,
                          int* __restrict__ wptr, int* __restrict__ scol, int E){
  int e = blockIdx.x * blockDim.x + threadIdx.x;
  if (e < E){
    int r = row[e];
    int pos = atomicAdd(&wptr[r], 1);
    scol[pos] = col[e];
  }
}

// ---------- sort each CSR row's columns (wave bitonic, <=64 elems) ----------
__global__ void k_sortrows(const int* __restrict__ rowptr, const int* __restrict__ cnt,
                           int* __restrict__ scol, int n_nodes){
  int n = blockIdx.x * 4 + (threadIdx.x >> 6);
  int lane = threadIdx.x & 63;
  if (n >= n_nodes) return;
  int c = cnt[n];
  if (c < 2 || c > 64) return;
  int beg = rowptr[n];
  int v = (lane < c) ? scol[beg + lane] : 0x7FFFFFFF;
  #pragma unroll
  for (int k = 2; k <= 64; k <<= 1){
    #pragma unroll
    for (int j = k >> 1; j > 0; j >>= 1){
      int o = __shfl_xor(v, j);
      bool dirUp = ((lane & k) == 0);
      bool takeMin = (((lane & j) == 0) == dirUp);
      int mn = (v < o) ? v : o;
      int mx = (v < o) ? o : v;
      v = takeMin ? mn : mx;
    }
  }
  if (lane < c) scol[beg + lane] = v;
}

// ---------- fused agg1 + MFMA GEMM2 (alpha2 folded as 2 extra cols) ----------
// 8 nodes/block, 512 threads (8 waves). Round-3 loop structure (compiler
// software-pipelines the 4 independent gathers); fp8 rows decoded with
// v_cvt_pk_f32_fp8 (1 op -> 2 floats).
__global__ void __launch_bounds__(512, 2)
k_agg1_gemm2(const unsigned char* __restrict__ Hb8, const float* __restrict__ a1s,
             const float* __restrict__ a1d, const int* __restrict__ rowptr,
             const int* __restrict__ cnt, const int* __restrict__ scol,
             const short* __restrict__ Bp2, bf16* __restrict__ h2b,
             float* __restrict__ a2s, float* __restrict__ a2d, int n_nodes){
  __shared__ short xh[8][528];   // elu(h_prime) hi bf16
  __shared__ short xl[8][528];   // lo bf16
  int n0   = blockIdx.x * 8;
  int wid  = threadIdx.x >> 6;
  int lane = threadIdx.x & 63;
  int hsel = lane >> 3;
  int n = n0 + wid;

  if (n < n_nodes){
    float asrc = a1s[n * NH + hsel];
    int beg = rowptr[n], endk = beg + cnt[n];
    f32x2 acc2[4] = {{0.f,0.f},{0.f,0.f},{0.f,0.f},{0.f,0.f}};
    float rsum = 0.f;
    int k = beg;
    for (; k + 3 < endk; k += 4){
      int c0 = scol[k], c1 = scol[k + 1], c2 = scol[k + 2], c3 = scol[k + 3];
      u32x2 q0 = *reinterpret_cast<const u32x2*>(Hb8 + (size_t)c0 * 512 + lane * 8);
      u32x2 q1 = *reinterpret_cast<const u32x2*>(Hb8 + (size_t)c1 * 512 + lane * 8);
      u32x2 q2 = *reinterpret_cast<const u32x2*>(Hb8 + (size_t)c2 * 512 + lane * 8);
      u32x2 q3 = *reinterpret_cast<const u32x2*>(Hb8 + (size_t)c3 * 512 + lane * 8);
      float s0 = asrc + a1d[c0 * NH + hsel];
      float s1 = asrc + a1d[c1 * NH + hsel];
      float s2 = asrc + a1d[c2 * NH + hsel];
      float s3 = asrc + a1d[c3 * NH + hsel];
      float l0 = fmaxf(s0, SLOPE * s0);
      float l1 = fmaxf(s1, SLOPE * s1);
      float l2 = fmaxf(s2, SLOPE * s2);
      float l3 = fmaxf(s3, SLOPE * s3);
      float e0 = __expf(-l0);
      float e1 = __expf(-l1);
      float e2 = __expf(-l2);
      float e3 = __expf(-l3);
      rsum += (e0 + e1) + (e2 + e3);
      f32x2 ev0 = {e0, e0}, ev1 = {e1, e1}, ev2 = {e2, e2}, ev3 = {e3, e3};
      acc2[0] += ev0 * __builtin_amdgcn_cvt_pk_f32_fp8(q0.x, false);
      acc2[1] += ev0 * __builtin_amdgcn_cvt_pk_f32_fp8(q0.x, true);
      acc2[2] += ev0 * __builtin_amdgcn_cvt_pk_f32_fp8(q0.y, false);
      acc2[3] += ev0 * __builtin_amdgcn_cvt_pk_f32_fp8(q0.y, true);
      acc2[0] += ev1 * __builtin_amdgcn_cvt_pk_f32_fp8(q1.x, false);
      acc2[1] += ev1 * __builtin_amdgcn_cvt_pk_f32_fp8(q1.x, true);
      acc2[2] += ev1 * __builtin_amdgcn_cvt_pk_f32_fp8(q1.y, false);
      acc2[3] += ev1 * __builtin_amdgcn_cvt_pk_f32_fp8(q1.y, true);
      acc2[0] += ev2 * __builtin_amdgcn_cvt_pk_f32_fp8(q2.x, false);
      acc2[1] += ev2 * __builtin_amdgcn_cvt_pk_f32_fp8(q2.x, true);
      acc2[2] += ev2 * __builtin_amdgcn_cvt_pk_f32_fp8(q2.y, false);
      acc2[3] += ev2 * __builtin_amdgcn_cvt_pk_f32_fp8(q2.y, true);
      acc2[0] += ev3 * __builtin_amdgcn_cvt_pk_f32_fp8(q3.x, false);
      acc2[1] += ev3 * __builtin_amdgcn_cvt_pk_f32_fp8(q3.x, true);
      acc2[2] += ev3 * __builtin_amdgcn_cvt_pk_f32_fp8(q3.y, false);
      acc2[3] += ev3 * __builtin_amdgcn_cvt_pk_f32_fp8(q3.y, true);
    }
    for (; k < endk; ++k){
      int c0 = scol[k];
      u32x2 q0 = *reinterpret_cast<const u32x2*>(Hb8 + (size_t)c0 * 512 + lane * 8);
      float s0 = asrc + a1d[c0 * NH + hsel];
      float l0 = fmaxf(s0, SLOPE * s0);
      float e0 = __expf(-l0);
      rsum += e0;
      f32x2 ev0 = {e0, e0};
      acc2[0] += ev0 * __builtin_amdgcn_cvt_pk_f32_fp8(q0.x, false);
      acc2[1] += ev0 * __builtin_amdgcn_cvt_pk_f32_fp8(q0.x, true);
      acc2[2] += ev0 * __builtin_amdgcn_cvt_pk_f32_fp8(q0.y, false);
      acc2[3] += ev0 * __builtin_amdgcn_cvt_pk_f32_fp8(q0.y, true);
    }
    float inv = 1.f / rsum;
    short8 hv8, lv8;
    #pragma unroll
    for (int jj = 0; jj < 8; jj++){
      float v = acc2[jj >> 1][jj & 1] * inv;
      v = (v > 0.f) ? v : (__expf(v) - 1.f);   // elu
      unsigned short hu = f2b_rne(v);
      float lof = v - us2f(hu);
      hv8[jj] = (short)hu;
      lv8[jj] = (short)f2b_rne(lof);
    }
    *reinterpret_cast<short8*>(&xh[wid][lane * 8]) = hv8;
    *reinterpret_cast<short8*>(&xl[wid][lane * 8]) = lv8;
  } else {
    short8 z = {0,0,0,0,0,0,0,0};
    *reinterpret_cast<short8*>(&xh[wid][lane * 8]) = z;
    *reinterpret_cast<short8*>(&xl[wid][lane * 8]) = z;
  }
  __syncthreads();

  // ---- phase 2+3: MFMA GEMM2; waves 0-3 -> h2b cols, wave 4 -> alpha2 ----
  if (wid < 5){
    int rowa = lane & 7;            // A rows 8-15 duplicate 0-7 (outputs discarded)
    int kg   = lane >> 4;
    f32x4 acc = {0.f, 0.f, 0.f, 0.f};
    #pragma unroll 4
    for (int ks = 0; ks < 16; ks++){
      short8 a_h = *reinterpret_cast<const short8*>(&xh[rowa][ks * 32 + kg * 8]);
      short8 a_l = *reinterpret_cast<const short8*>(&xl[rowa][ks * 32 + kg * 8]);
      short8 b_h = *reinterpret_cast<const short8*>(Bp2 + ((size_t)(ks * 5) + wid) * 512 + lane * 8);
      short8 b_l = *reinterpret_cast<const short8*>(Bp2 + ((size_t)((16 + ks) * 5) + wid) * 512 + lane * 8);
      acc = mfma16(a_h, b_h, acc);
      acc = mfma16(a_l, b_h, acc);
      acc = mfma16(a_h, b_l, acc);
    }
    int cl = lane & 15;
    if (kg < 2){                    // D rows 0-7 = our 8 nodes
      #pragma unroll
      for (int reg = 0; reg < 4; reg++){
        int nn = n0 + kg * 4 + reg;
        if (nn < n_nodes){
          if (wid < 4){
            h2b[(size_t)nn * 64 + wid * 16 + cl] = f2b(acc[reg]);
          } else if (cl == 0){
            a2s[nn] = acc[reg];
          } else if (cl == 1){
            a2d[nn] = acc[reg];
          }
        }
      }
    }
  }
}

// ---------- aggregation layer 2: 8 nodes/wave, 8-lane groups, 16B row slices ----------
// Each group (8 lanes) owns one node; sub-lane sl covers 8 features (bf16x8 = 16B).
// One wave-instruction gathers 8 independent rows -> 8 latency chains; unroll-2 -> 16.
// Masked loop to max-deg over the wave's 8 groups (deg >= 1 via self-loops).
__global__ void __launch_bounds__(256)
k_agg2(const bf16* __restrict__ h2b, const float* __restrict__ a2s,
       const float* __restrict__ a2d, const int* __restrict__ rowptr,
       const int* __restrict__ cnt, const int* __restrict__ scol,
       float* __restrict__ xo, int n_nodes){
  int wid  = threadIdx.x >> 6;
  int lane = threadIdx.x & 63;
  int g = lane >> 3, sl = lane & 7;
  int n = blockIdx.x * 32 + wid * 8 + g;
  bool nv = (n < n_nodes);
  int beg = 0, deg = 0;
  float asrc = 0.f;
  if (nv){ beg = rowptr[n]; deg = cnt[n]; asrc = a2s[n]; }
  int mdeg = deg;
  #pragma unroll
  for (int m = 8; m < 64; m <<= 1){
    int o = __shfl_xor(mdeg, m);
    mdeg = (o > mdeg) ? o : mdeg;
  }
  f32x2 acc2[4] = {{0.f,0.f},{0.f,0.f},{0.f,0.f},{0.f,0.f}};
  float rsum = 0.f;
  int it = 0;
  for (; it + 1 < mdeg; it += 2){
    int i0 = (it     < deg) ? it     : 0;
    int i1 = (it + 1 < deg) ? it + 1 : 0;
    int c0 = scol[beg + i0];
    int c1 = scol[beg + i1];
    uint4v h0 = *reinterpret_cast<const uint4v*>(h2b + ((size_t)c0 << 6) + sl * 8);
    uint4v h1 = *reinterpret_cast<const uint4v*>(h2b + ((size_t)c1 << 6) + sl * 8);
    float s0 = asrc + a2d[c0];
    float s1 = asrc + a2d[c1];
    float l0 = fmaxf(s0, SLOPE * s0);
    float l1 = fmaxf(s1, SLOPE * s1);
    float e0 = __expf(-l0);
    float e1 = __expf(-l1);
    e0 = (it     < deg) ? e0 : 0.f;
    e1 = (it + 1 < deg) ? e1 : 0.f;
    rsum += e0 + e1;
    f32x2 ev0 = {e0, e0}, ev1 = {e1, e1};
    #pragma unroll
    for (int d = 0; d < 4; d++){
      f32x2 hv0 = {lo16(h0[d]), hi16(h0[d])};
      f32x2 hv1 = {lo16(h1[d]), hi16(h1[d])};
      acc2[d] += ev0 * hv0 + ev1 * hv1;
    }
  }
  if (it < mdeg){
    int i0 = (it < deg) ? it : 0;
    int c0 = scol[beg + i0];
    uint4v h0 = *reinterpret_cast<const uint4v*>(h2b + ((size_t)c0 << 6) + sl * 8);
    float s0 = asrc + a2d[c0];
    float l0 = fmaxf(s0, SLOPE * s0);
    float e0 = __expf(-l0);
    e0 = (it < deg) ? e0 : 0.f;
    rsum += e0;
    f32x2 ev0 = {e0, e0};
    #pragma unroll
    for (int d = 0; d < 4; d++){
      f32x2 hv0 = {lo16(h0[d]), hi16(h0[d])};
      acc2[d] += ev0 * hv0;
    }
  }
  if (nv){
    float inv = 1.f / rsum;
    float4 lo, hi;
    float vv[8];
    #pragma unroll
    for (int jj = 0; jj < 8; jj++){
      float v = acc2[jj >> 1][jj & 1] * inv;
      vv[jj] = (v > 0.f) ? v : (__expf(v) - 1.f);   // elu after layer 2
    }
    lo.x = vv[0]; lo.y = vv[1]; lo.z = vv[2]; lo.w = vv[3];
    hi.x = vv[4]; hi.y = vv[5]; hi.z = vv[6]; hi.w = vv[7];
    *reinterpret_cast<float4*>(xo + (size_t)n * 64 + sl * 8)     = lo;
    *reinterpret_cast<float4*>(xo + (size_t)n * 64 + sl * 8 + 4) = hi;
  }
}

// ---------- MLP head: MFMA for W1 stage, 16 nodes/block ----------
__global__ void __launch_bounds__(256)
k_mlp(const float* __restrict__ xo, const short* __restrict__ Bp3,
      const float* __restrict__ b1, const float* __restrict__ W2,
      const float* __restrict__ b2, const float* __restrict__ W3,
      const float* __restrict__ b3, float* __restrict__ out, int n_nodes){
  __shared__ short xsh[16][72];
  __shared__ short xsl[16][72];
  __shared__ float z1[16][650];   // 650: conflict-free kg groups
  __shared__ float z2[16][10];
  int n0 = blockIdx.x * 16;
  int t  = threadIdx.x;
  for (int i = t; i < 16 * 64; i += 256){
    int r = i >> 6, c = i & 63;
    int nn = n0 + r;
    float v = (nn < n_nodes) ? xo[(size_t)nn * 64 + c] : 0.f;
    unsigned short hu = f2b_rne(v);
    float lof = v - us2f(hu);
    xsh[r][c] = (short)hu;
    xsl[r][c] = (short)f2b_rne(lof);
  }
  __syncthreads();
  int wid = t >> 6, lane = t & 63;
  int rowa = lane & 15, kg = lane >> 4, cl = lane & 15;
  short8 ah[2], al[2];
  #pragma unroll
  for (int ks = 0; ks < 2; ks++){
    ah[ks] = *reinterpret_cast<const short8*>(&xsh[rowa][ks * 32 + kg * 8]);
    al[ks] = *reinterpret_cast<const short8*>(&xsl[rowa][ks * 32 + kg * 8]);
  }
  for (int f0 = 0; f0 < 10; f0++){
    int f = wid * 10 + f0;
    f32x4 acc = {0.f, 0.f, 0.f, 0.f};
    #pragma unroll
    for (int ks = 0; ks < 2; ks++){
      short8 b_h = *reinterpret_cast<const short8*>(Bp3 + ((size_t)(ks * 40) + f) * 512 + lane * 8);
      short8 b_l = *reinterpret_cast<const short8*>(Bp3 + ((size_t)((2 + ks) * 40) + f) * 512 + lane * 8);
      acc = mfma16(ah[ks], b_h, acc);
      acc = mfma16(al[ks], b_h, acc);
      acc = mfma16(ah[ks], b_l, acc);
    }
    int cc = f * 16 + cl;
    float bb = b1[cc];
    #pragma unroll
    for (int reg = 0; reg < 4; reg++)
      z1[kg * 4 + reg][cc] = fmaxf(acc[reg] + bb, 0.f);
  }
  __syncthreads();
  {
    int g = t >> 4, sub = t & 15;
    float p[10];
    #pragma unroll
    for (int kk = 0; kk < 10; kk++) p[kk] = 0.f;
    for (int jj = 0; jj < 40; jj++){
      int j = sub + jj * 16;
      float v = z1[g][j];
      #pragma unroll
      for (int kk = 0; kk < 10; kk++) p[kk] += v * W2[j * 10 + kk];
    }
    #pragma unroll
    for (int kk = 0; kk < 10; kk++){
      #pragma unroll
      for (int m = 8; m; m >>= 1) p[kk] += __shfl_xor(p[kk], m);
    }
    if (sub == 0){
      #pragma unroll
      for (int kk = 0; kk < 10; kk++) z2[g][kk] = fmaxf(p[kk] + b2[kk], 0.f);
    }
  }
  __syncthreads();
  if (t < 16){
    int nn = n0 + t;
    if (nn < n_nodes){
      float acc = b3[0];
      #pragma unroll
      for (int kk = 0; kk < 10; kk++) acc += z2[t][kk] * W3[kk];
      out[nn] = 1.f / (1.f + __expf(-acc));
    }
  }
}

extern "C" void kernel_launch(void* const* d_in, const int* in_sizes, int n_in,
                              void* d_out, int out_size, void* d_ws, size_t ws_size,
                              hipStream_t stream){
  const float* x    = (const float*)d_in[0];
  const int*   ei   = (const int*)  d_in[1];
  const float* Watt = (const float*)d_in[2];
  const float* aatt = (const float*)d_in[3];
  const float* Wout = (const float*)d_in[4];
  const float* aout = (const float*)d_in[5];
  const float* W1   = (const float*)d_in[6];
  const float* b1   = (const float*)d_in[7];
  const float* W2   = (const float*)d_in[8];
  const float* b2   = (const float*)d_in[9];
  const float* W3   = (const float*)d_in[10];
  const float* b3   = (const float*)d_in[11];
  float* out = (float*)d_out;

  int N = in_sizes[0] / NF;
  int E = in_sizes[1] / 2;
  const int* row = ei;
  const int* col = ei + E;

  char* base = (char*)d_ws;
  size_t off = 0;
  auto alloc = [&](size_t bytes) -> void* {
    void* p = base + off;
    off = (off + bytes + 255) & ~(size_t)255;
    return p;
  };
  unsigned char* Hb8 = (unsigned char*)alloc((size_t)N * 512);   // 51.2 MB fp8
  bf16*  h2b    = (bf16*) alloc((size_t)N * 64 * 2);   // 12.8 MB
  float* xo     = (float*)alloc((size_t)N * 64 * 4);   // 25.6 MB
  float* a1s    = (float*)alloc((size_t)N * NH * 4);
  float* a1d    = (float*)alloc((size_t)N * NH * 4);
  float* a2s    = (float*)alloc((size_t)N * 4);
  float* a2d    = (float*)alloc((size_t)N * 4);
  int*   cnt    = (int*)  alloc((size_t)N * 4);
  int*   rowptr = (int*)  alloc((size_t)N * 4);
  int*   wptr   = (int*)  alloc((size_t)N * 4);
  int*   incl   = (int*)  alloc((size_t)N * 4);
  int    NB     = (N + 1023) / 1024;
  int*   bsum   = (int*)  alloc((size_t)NB * 4);
  int*   boff   = (int*)  alloc((size_t)NB * 4);
  int*   scol   = (int*)  alloc((size_t)E * 4);        // 6.4 MB
  short* Bp1    = (short*)alloc((size_t)4 * 33 * 512 * 2);   // 135 KB packed W_att|alpha1
  short* Bp2    = (short*)alloc((size_t)32 * 5 * 512 * 2);   // 160 KB packed Wout|alpha2
  short* Bp3    = (short*)alloc((size_t)4 * 40 * 512 * 2);   // 160 KB packed W1
  (void)ws_size; (void)n_in; (void)out_size;

  hipMemsetAsync(cnt, 0, (size_t)N * 4, stream);

  k_prep1     <<<66,              64, 0, stream>>>(Watt, aatt, Bp1);
  k_prep2     <<<80,              64, 0, stream>>>(Wout, aout, Bp2);
  k_prep3     <<<80,              64, 0, stream>>>(W1, Bp3);
  k_gemm1_mfma<<<(N + 15) / 16,  256, 0, stream>>>(x, Bp1, Hb8, a1s, a1d, N);
  k_count     <<<(E + 255) / 256, 256, 0, stream>>>(row, cnt, E);
  k_scan_a    <<<NB,             1024, 0, stream>>>(cnt, incl, bsum, N);
  k_scan_b    <<<1,               128, 0, stream>>>(bsum, boff, NB);
  k_scan_c    <<<NB,             1024, 0, stream>>>(incl, cnt, boff, rowptr, wptr, N);
  k_scatter   <<<(E + 255) / 256, 256, 0, stream>>>(row, col, wptr, scol, E);
  k_sortrows  <<<(N + 3) / 4,     256, 0, stream>>>(rowptr, cnt, scol, N);
  k_agg1_gemm2<<<(N + 7) / 8,     512, 0, stream>>>(Hb8, a1s, a1d, rowptr, cnt, scol,
                                                    Bp2, h2b, a2s, a2d, N);
  k_agg2      <<<(N + 31) / 32,  256, 0, stream>>>(h2b, a2s, a2d, rowptr, cnt, scol, xo, N);
  k_mlp       <<<(N + 15) / 16,  256, 0, stream>>>(xo, Bp3, b1, W2, b2, W3, b3, out, N);
}

// Round 7
// 694.001 us; speedup vs baseline: 1.1968x; 1.0239x over previous
//
#include <hip/hip_runtime.h>
#include <hip/hip_bf16.h>
#include <math.h>

#define NF 64
#define NH 8
#define SLOPE 0.2f

typedef __hip_bfloat16 bf16;
typedef short short8 __attribute__((ext_vector_type(8)));
typedef unsigned int u32x2 __attribute__((ext_vector_type(2)));
typedef unsigned int uint4v __attribute__((ext_vector_type(4)));
typedef float f32x4 __attribute__((ext_vector_type(4)));
typedef float f32x2 __attribute__((ext_vector_type(2)));

__device__ __forceinline__ float b2f(bf16 v){ return __bfloat162float(v); }
__device__ __forceinline__ bf16 f2b(float v){ return __float2bfloat16(v); }
__device__ __forceinline__ float us2f(unsigned short u){
  union{ unsigned int i; float f; } c; c.i = ((unsigned int)u) << 16; return c.f;
}
// unpack packed 2xbf16 dword -> f32 (low / high element)
__device__ __forceinline__ float lo16(unsigned int u){
  union{ unsigned int i; float f; } c; c.i = u << 16; return c.f;
}
__device__ __forceinline__ float hi16(unsigned int u){
  union{ unsigned int i; float f; } c; c.i = u & 0xFFFF0000u; return c.f;
}
// round-to-nearest-even f32 -> bf16 bits
__device__ __forceinline__ unsigned short f2b_rne(float v){
  union{ float f; unsigned int i; } c; c.f = v;
  unsigned int b = c.i + 0x7FFF + ((c.i >> 16) & 1);
  return (unsigned short)(b >> 16);
}
__device__ __forceinline__ f32x4 mfma16(short8 a, short8 b, f32x4 c){
  return __builtin_amdgcn_mfma_f32_16x16x32_bf16(a, b, c, 0, 0, 0);
}

// ---------- weight pre-pack kernels (tiny, run once per launch) ----------
// B-fragment layout for mfma_f32_16x16x32_bf16: b[j] = B[(lane>>4)*8+j][lane&15]
// Packed as [term(hi=0,lo=1)][ks][frag][lane][j] -> coalesced short8 per lane.

// GEMM1: B = [W_att heads (512 cols) | W@a_src (8) | W@a_dst (8)] : 64 x 528, 33 frags, 2 ks
// frags 0..31 double as the per-head W fragments for agg1's phase-2a (head w = frags 4w..4w+3).
__global__ void k_prep1(const float* __restrict__ Watt, const float* __restrict__ aatt,
                        short* __restrict__ Bp1){
  int f = blockIdx.x >> 1, ks = blockIdx.x & 1;
  int lane = threadIdx.x;
  int kg = lane >> 4, cl = lane & 15;
  int col = f * 16 + cl;
  for (int j = 0; j < 8; j++){
    int k = ks * 32 + kg * 8 + j;
    float val;
    if (col < 512){
      val = Watt[(size_t)(col >> 6) * 4096 + k * 64 + (col & 63)];
    } else {
      int h = (col - 512) & 7;
      const float* arow = aatt + h * 128 + ((col >= 520) ? 64 : 0);
      const float* wrow = Watt + (size_t)h * 4096 + k * 64;
      float s = 0.f;
      for (int d = 0; d < 64; d++) s += wrow[d] * arow[d];
      val = s;
    }
    unsigned short hu = f2b_rne(val);
    float lof = val - us2f(hu);
    Bp1[((size_t)(ks * 33) + f) * 512 + lane * 8 + j]       = (short)hu;
    Bp1[((size_t)((2 + ks) * 33) + f) * 512 + lane * 8 + j] = (short)f2b_rne(lof);
  }
}

// GEMM2: B = [Wout (64 cols) | Wout@aout_s | Wout@aout_d | pad] : 512 x 80, 5 frags, 16 ks
__global__ void k_prep2(const float* __restrict__ Wout, const float* __restrict__ aout,
                        short* __restrict__ Bp2){
  int f = blockIdx.x >> 4, ks = blockIdx.x & 15;
  int lane = threadIdx.x;
  int kg = lane >> 4, cl = lane & 15;
  int col = f * 16 + cl;
  for (int j = 0; j < 8; j++){
    int k = ks * 32 + kg * 8 + j;
    float val = 0.f;
    if (col < 64){
      val = Wout[(size_t)k * 64 + col];
    } else if (col == 64 || col == 65){
      const float* arow = aout + ((col == 65) ? 64 : 0);
      const float* wrow = Wout + (size_t)k * 64;
      float s = 0.f;
      for (int d = 0; d < 64; d++) s += wrow[d] * arow[d];
      val = s;
    }
    unsigned short hu = f2b_rne(val);
    float lof = val - us2f(hu);
    Bp2[((size_t)(ks * 5) + f) * 512 + lane * 8 + j]        = (short)hu;
    Bp2[((size_t)((16 + ks) * 5) + f) * 512 + lane * 8 + j] = (short)f2b_rne(lof);
  }
}

// MLP1: B = W1 : 64 x 640, 40 frags, 2 ks
__global__ void k_prep3(const float* __restrict__ W1, short* __restrict__ Bp3){
  int f = blockIdx.x >> 1, ks = blockIdx.x & 1;
  int lane = threadIdx.x;
  int kg = lane >> 4, cl = lane & 15;
  int col = f * 16 + cl;
  for (int j = 0; j < 8; j++){
    int k = ks * 32 + kg * 8 + j;
    float val = W1[(size_t)k * 640 + col];
    unsigned short hu = f2b_rne(val);
    float lof = val - us2f(hu);
    Bp3[((size_t)(ks * 40) + f) * 512 + lane * 8 + j]       = (short)hu;
    Bp3[((size_t)((2 + ks) * 40) + f) * 512 + lane * 8 + j] = (short)f2b_rne(lof);
  }
}

// ---------- prep_x: xb = bf16(x) (gather payload for agg1) + alpha1 GEMM ----------
// 16 nodes/block, 256 threads. Alpha scores via the folded x @ (W@a) columns of Bp1.
__global__ void __launch_bounds__(256)
k_prep_x(const float* __restrict__ x, const short* __restrict__ Bp1,
         short* __restrict__ xb, float* __restrict__ a1s, float* __restrict__ a1d,
         int n_nodes){
  __shared__ short xsh[16][72];   // hi bf16
  __shared__ short xsl[16][72];   // lo bf16
  int n0 = blockIdx.x * 16;
  int t = threadIdx.x;
  for (int i = t; i < 16 * 64; i += 256){
    int r = i >> 6, c = i & 63;
    int nn = n0 + r;
    float v = (nn < n_nodes) ? x[(size_t)nn * NF + c] : 0.f;
    unsigned short hu = f2b_rne(v);
    float lof = v - us2f(hu);
    xsh[r][c] = (short)hu;
    xsl[r][c] = (short)f2b_rne(lof);
  }
  __syncthreads();
  // coalesced xb write (hi bf16 only: gather payload)
  for (int i = t; i < 16 * 8; i += 256){
    int r = i >> 3, c8 = (i & 7) * 8;
    int nn = n0 + r;
    if (nn < n_nodes)
      *reinterpret_cast<short8*>(xb + (size_t)nn * 64 + c8) =
        *reinterpret_cast<const short8*>(&xsh[r][c8]);
  }
  int wid = t >> 6, lane = t & 63;
  if (wid == 3){                       // alpha frag (f=32): 16 alpha cols
    int rowa = lane & 15, kg = lane >> 4, cl = lane & 15;
    short8 ah[2], al[2];
    #pragma unroll
    for (int ks = 0; ks < 2; ks++){
      ah[ks] = *reinterpret_cast<const short8*>(&xsh[rowa][ks * 32 + kg * 8]);
      al[ks] = *reinterpret_cast<const short8*>(&xsl[rowa][ks * 32 + kg * 8]);
    }
    f32x4 acc = {0.f, 0.f, 0.f, 0.f};
    #pragma unroll
    for (int ks = 0; ks < 2; ks++){
      short8 b_h = *reinterpret_cast<const short8*>(Bp1 + ((size_t)(ks * 33) + 32) * 512 + lane * 8);
      short8 b_l = *reinterpret_cast<const short8*>(Bp1 + ((size_t)((2 + ks) * 33) + 32) * 512 + lane * 8);
      acc = mfma16(ah[ks], b_h, acc);
      acc = mfma16(al[ks], b_h, acc);
      acc = mfma16(ah[ks], b_l, acc);
    }
    #pragma unroll
    for (int reg = 0; reg < 4; reg++){
      int nn = n0 + kg * 4 + reg;
      if (nn < n_nodes){
        if (cl < 8) a1s[nn * NH + cl] = acc[reg];
        else        a1d[nn * NH + (cl - 8)] = acc[reg];
      }
    }
  }
}

// ---------- CSR build ----------
__global__ void k_count(const int* __restrict__ row, int* __restrict__ cnt, int E){
  int e = blockIdx.x * blockDim.x + threadIdx.x;
  if (e < E) atomicAdd(&cnt[row[e]], 1);
}

__global__ void k_scan_a(const int* __restrict__ cnt, int* __restrict__ incl,
                         int* __restrict__ bsum, int n){
  __shared__ int s[1024];
  int i = blockIdx.x * 1024 + threadIdx.x;
  int v = (i < n) ? cnt[i] : 0;
  s[threadIdx.x] = v;
  __syncthreads();
  for (int d = 1; d < 1024; d <<= 1){
    int tv = (threadIdx.x >= d) ? s[threadIdx.x - d] : 0;
    __syncthreads();
    s[threadIdx.x] += tv;
    __syncthreads();
  }
  if (i < n) incl[i] = s[threadIdx.x];
  if (threadIdx.x == 1023) bsum[blockIdx.x] = s[1023];
}

__global__ void k_scan_b(const int* __restrict__ bsum, int* __restrict__ boff, int nb){
  __shared__ int s[128];
  int t = threadIdx.x;
  if (nb <= 128){
    int v = (t < nb) ? bsum[t] : 0;
    s[t] = v;
    __syncthreads();
    for (int d = 1; d < 128; d <<= 1){
      int tv = (t >= d) ? s[t - d] : 0;
      __syncthreads();
      s[t] += tv;
      __syncthreads();
    }
    if (t < nb) boff[t] = s[t] - v;   // exclusive
  } else if (t == 0){
    int run = 0;
    for (int b = 0; b < nb; b++){ boff[b] = run; run += bsum[b]; }
  }
}

__global__ void k_scan_c(const int* __restrict__ incl, const int* __restrict__ cnt,
                         const int* __restrict__ boff, int* __restrict__ rowptr,
                         int* __restrict__ wptr, int n){
  int i = blockIdx.x * 1024 + threadIdx.x;
  if (i < n){
    int start = incl[i] - cnt[i] + boff[blockIdx.x];
    rowptr[i] = start;
    wptr[i]   = start;
  }
}

__global__ void k_scatter(const int* __restrict__ row, const int* __restrict__ col,
                          int* __restrict__ wptr, int* __restrict__ scol, int E){
  int e = blockIdx.x * blockDim.x + threadIdx.x;
  if (e < E){
    int r = row[e];
    int pos = atomicAdd(&wptr[r], 1);
    scol[pos] = col[e];
  }
}

// ---------- fused agg1 (input-side, linearity trick) + per-head W MFMA + Wout MFMA ----------
// 8 nodes/block, 512 threads (8 waves), 1 node/wave.
// Phase 1: aggregate G[h][feat] = sum_c e_c^h * xb[c][feat] over the node's edges.
//   Lane = (head h = lane>>3, slice q = lane&7); lane holds feats q*8..q*8+7 of head h.
//   Gather payload: 128 B/edge from the 12.8 MB L2-resident xb (vs 512 B of H before).
// Phase 2a: h'_head = (G_h / rsum) @ W_head via MFMA (wave w = head w, Bp1 frags 4w..4w+3),
//   then ELU -> xh (8 x 512 bf16 hi/lo).
// Phase 2b: unchanged Wout GEMM (alpha2 folded).
__global__ void __launch_bounds__(512, 2)
k_agg1_gemm2(const short* __restrict__ xb, const float* __restrict__ a1s,
             const float* __restrict__ a1d, const int* __restrict__ rowptr,
             const int* __restrict__ cnt, const int* __restrict__ scol,
             const short* __restrict__ Bp1, const short* __restrict__ Bp2,
             bf16* __restrict__ h2b, float* __restrict__ a2s,
             float* __restrict__ a2d, int n_nodes){
  __shared__ short Gh[8 * 600];  // [node][h*72 + feat], stride 600: conflict-free b128 frag reads
  __shared__ short Gl[8 * 600];
  __shared__ short xh[8][528];   // elu(h') hi bf16
  __shared__ short xl[8][528];   // lo bf16
  int n0   = blockIdx.x * 8;
  int wid  = threadIdx.x >> 6;
  int lane = threadIdx.x & 63;
  int h = lane >> 3, q = lane & 7;
  int n = n0 + wid;
  int gidx = wid * 600 + h * 72 + q * 8;

  if (n < n_nodes){
    float asrc = a1s[n * NH + h];
    int beg = rowptr[n], endk = beg + cnt[n];
    f32x2 acc2[4] = {{0.f,0.f},{0.f,0.f},{0.f,0.f},{0.f,0.f}};
    float rsum = 0.f;
    int k = beg;
    for (; k + 3 < endk; k += 4){
      int c0 = scol[k], c1 = scol[k + 1], c2 = scol[k + 2], c3 = scol[k + 3];
      uint4v x0 = *reinterpret_cast<const uint4v*>(xb + (size_t)c0 * 64 + q * 8);
      uint4v x1 = *reinterpret_cast<const uint4v*>(xb + (size_t)c1 * 64 + q * 8);
      uint4v x2 = *reinterpret_cast<const uint4v*>(xb + (size_t)c2 * 64 + q * 8);
      uint4v x3 = *reinterpret_cast<const uint4v*>(xb + (size_t)c3 * 64 + q * 8);
      float s0 = asrc + a1d[c0 * NH + h];
      float s1 = asrc + a1d[c1 * NH + h];
      float s2 = asrc + a1d[c2 * NH + h];
      float s3 = asrc + a1d[c3 * NH + h];
      float l0 = fmaxf(s0, SLOPE * s0);
      float l1 = fmaxf(s1, SLOPE * s1);
      float l2 = fmaxf(s2, SLOPE * s2);
      float l3 = fmaxf(s3, SLOPE * s3);
      float e0 = __expf(-l0);
      float e1 = __expf(-l1);
      float e2 = __expf(-l2);
      float e3 = __expf(-l3);
      rsum += (e0 + e1) + (e2 + e3);
      f32x2 ev0 = {e0, e0}, ev1 = {e1, e1}, ev2 = {e2, e2}, ev3 = {e3, e3};
      #pragma unroll
      for (int d = 0; d < 4; d++){
        f32x2 hv0 = {lo16(x0[d]), hi16(x0[d])};
        f32x2 hv1 = {lo16(x1[d]), hi16(x1[d])};
        f32x2 hv2 = {lo16(x2[d]), hi16(x2[d])};
        f32x2 hv3 = {lo16(x3[d]), hi16(x3[d])};
        acc2[d] += (ev0 * hv0 + ev1 * hv1) + (ev2 * hv2 + ev3 * hv3);
      }
    }
    for (; k < endk; ++k){
      int c0 = scol[k];
      uint4v x0 = *reinterpret_cast<const uint4v*>(xb + (size_t)c0 * 64 + q * 8);
      float s0 = asrc + a1d[c0 * NH + h];
      float l0 = fmaxf(s0, SLOPE * s0);
      float e0 = __expf(-l0);
      rsum += e0;
      f32x2 ev0 = {e0, e0};
      #pragma unroll
      for (int d = 0; d < 4; d++){
        f32x2 hv0 = {lo16(x0[d]), hi16(x0[d])};
        acc2[d] += ev0 * hv0;
      }
    }
    float inv = 1.f / rsum;
    #pragma unroll
    for (int jj = 0; jj < 8; jj++){
      float v = acc2[jj >> 1][jj & 1] * inv;
      unsigned short hu = f2b_rne(v);
      Gh[gidx + jj] = (short)hu;
      Gl[gidx + jj] = (short)f2b_rne(v - us2f(hu));
    }
  } else {
    #pragma unroll
    for (int jj = 0; jj < 8; jj++){ Gh[gidx + jj] = 0; Gl[gidx + jj] = 0; }
  }
  __syncthreads();

  // ---- phase 2a: per-head W GEMM; wave w = head w; ELU epilogue -> xh ----
  {
    int rowa = lane & 7;            // A rows 8-15 duplicate 0-7 (outputs discarded)
    int kg   = lane >> 4, cl = lane & 15;
    short8 gah[2], gal[2];
    #pragma unroll
    for (int ks = 0; ks < 2; ks++){
      gah[ks] = *reinterpret_cast<const short8*>(&Gh[rowa * 600 + wid * 72 + ks * 32 + kg * 8]);
      gal[ks] = *reinterpret_cast<const short8*>(&Gl[rowa * 600 + wid * 72 + ks * 32 + kg * 8]);
    }
    #pragma unroll
    for (int fc = 0; fc < 4; fc++){
      int f = wid * 4 + fc;
      f32x4 acc = {0.f, 0.f, 0.f, 0.f};
      #pragma unroll
      for (int ks = 0; ks < 2; ks++){
        short8 b_h = *reinterpret_cast<const short8*>(Bp1 + ((size_t)(ks * 33) + f) * 512 + lane * 8);
        short8 b_l = *reinterpret_cast<const short8*>(Bp1 + ((size_t)((2 + ks) * 33) + f) * 512 + lane * 8);
        acc = mfma16(gah[ks], b_h, acc);
        acc = mfma16(gal[ks], b_h, acc);
        acc = mfma16(gah[ks], b_l, acc);
      }
      if (kg < 2){                  // D rows 0-7 = the 8 nodes
        #pragma unroll
        for (int reg = 0; reg < 4; reg++){
          int r = kg * 4 + reg;
          float v = acc[reg];
          v = (v > 0.f) ? v : (__expf(v) - 1.f);   // elu
          unsigned short hu = f2b_rne(v);
          xh[r][wid * 64 + fc * 16 + cl] = (short)hu;
          xl[r][wid * 64 + fc * 16 + cl] = (short)f2b_rne(v - us2f(hu));
        }
      }
    }
  }
  __syncthreads();

  // ---- phase 2b: Wout MFMA; waves 0-3 -> h2b cols, wave 4 -> alpha2 ----
  if (wid < 5){
    int rowa = lane & 7;
    int kg   = lane >> 4;
    f32x4 acc = {0.f, 0.f, 0.f, 0.f};
    #pragma unroll 4
    for (int ks = 0; ks < 16; ks++){
      short8 a_h = *reinterpret_cast<const short8*>(&xh[rowa][ks * 32 + kg * 8]);
      short8 a_l = *reinterpret_cast<const short8*>(&xl[rowa][ks * 32 + kg * 8]);
      short8 b_h = *reinterpret_cast<const short8*>(Bp2 + ((size_t)(ks * 5) + wid) * 512 + lane * 8);
      short8 b_l = *reinterpret_cast<const short8*>(Bp2 + ((size_t)((16 + ks) * 5) + wid) * 512 + lane * 8);
      acc = mfma16(a_h, b_h, acc);
      acc = mfma16(a_l, b_h, acc);
      acc = mfma16(a_h, b_l, acc);
    }
    int cl = lane & 15;
    if (kg < 2){
      #pragma unroll
      for (int reg = 0; reg < 4; reg++){
        int nn = n0 + kg * 4 + reg;
        if (nn < n_nodes){
          if (wid < 4){
            h2b[(size_t)nn * 64 + wid * 16 + cl] = f2b(acc[reg]);
          } else if (cl == 0){
            a2s[nn] = acc[reg];
          } else if (cl == 1){
            a2d[nn] = acc[reg];
          }
        }
      }
    }
  }
}

// ---------- aggregation layer 2: 8 nodes/wave, 8-lane groups, 16B row slices ----------
__global__ void __launch_bounds__(256)
k_agg2(const bf16* __restrict__ h2b, const float* __restrict__ a2s,
       const float* __restrict__ a2d, const int* __restrict__ rowptr,
       const int* __restrict__ cnt, const int* __restrict__ scol,
       float* __restrict__ xo, int n_nodes){
  int wid  = threadIdx.x >> 6;
  int lane = threadIdx.x & 63;
  int g = lane >> 3, sl = lane & 7;
  int n = blockIdx.x * 32 + wid * 8 + g;
  bool nv = (n < n_nodes);
  int beg = 0, deg = 0;
  float asrc = 0.f;
  if (nv){ beg = rowptr[n]; deg = cnt[n]; asrc = a2s[n]; }
  int mdeg = deg;
  #pragma unroll
  for (int m = 8; m < 64; m <<= 1){
    int o = __shfl_xor(mdeg, m);
    mdeg = (o > mdeg) ? o : mdeg;
  }
  f32x2 acc2[4] = {{0.f,0.f},{0.f,0.f},{0.f,0.f},{0.f,0.f}};
  float rsum = 0.f;
  int it = 0;
  for (; it + 1 < mdeg; it += 2){
    int i0 = (it     < deg) ? it     : 0;
    int i1 = (it + 1 < deg) ? it + 1 : 0;
    int c0 = scol[beg + i0];
    int c1 = scol[beg + i1];
    uint4v h0 = *reinterpret_cast<const uint4v*>(h2b + ((size_t)c0 << 6) + sl * 8);
    uint4v h1 = *reinterpret_cast<const uint4v*>(h2b + ((size_t)c1 << 6) + sl * 8);
    float s0 = asrc + a2d[c0];
    float s1 = asrc + a2d[c1];
    float l0 = fmaxf(s0, SLOPE * s0);
    float l1 = fmaxf(s1, SLOPE * s1);
    float e0 = __expf(-l0);
    float e1 = __expf(-l1);
    e0 = (it     < deg) ? e0 : 0.f;
    e1 = (it + 1 < deg) ? e1 : 0.f;
    rsum += e0 + e1;
    f32x2 ev0 = {e0, e0}, ev1 = {e1, e1};
    #pragma unroll
    for (int d = 0; d < 4; d++){
      f32x2 hv0 = {lo16(h0[d]), hi16(h0[d])};
      f32x2 hv1 = {lo16(h1[d]), hi16(h1[d])};
      acc2[d] += ev0 * hv0 + ev1 * hv1;
    }
  }
  if (it < mdeg){
    int i0 = (it < deg) ? it : 0;
    int c0 = scol[beg + i0];
    uint4v h0 = *reinterpret_cast<const uint4v*>(h2b + ((size_t)c0 << 6) + sl * 8);
    float s0 = asrc + a2d[c0];
    float l0 = fmaxf(s0, SLOPE * s0);
    float e0 = __expf(-l0);
    e0 = (it < deg) ? e0 : 0.f;
    rsum += e0;
    f32x2 ev0 = {e0, e0};
    #pragma unroll
    for (int d = 0; d < 4; d++){
      f32x2 hv0 = {lo16(h0[d]), hi16(h0[d])};
      acc2[d] += ev0 * hv0;
    }
  }
  if (nv){
    float inv = 1.f / rsum;
    float4 lo, hi;
    float vv[8];
    #pragma unroll
    for (int jj = 0; jj < 8; jj++){
      float v = acc2[jj >> 1][jj & 1] * inv;
      vv[jj] = (v > 0.f) ? v : (__expf(v) - 1.f);   // elu after layer 2
    }
    lo.x = vv[0]; lo.y = vv[1]; lo.z = vv[2]; lo.w = vv[3];
    hi.x = vv[4]; hi.y = vv[5]; hi.z = vv[6]; hi.w = vv[7];
    *reinterpret_cast<float4*>(xo + (size_t)n * 64 + sl * 8)     = lo;
    *reinterpret_cast<float4*>(xo + (size_t)n * 64 + sl * 8 + 4) = hi;
  }
}

// ---------- MLP head: MFMA for W1 stage, 16 nodes/block ----------
__global__ void __launch_bounds__(256)
k_mlp(const float* __restrict__ xo, const short* __restrict__ Bp3,
      const float* __restrict__ b1, const float* __restrict__ W2,
      const float* __restrict__ b2, const float* __restrict__ W3,
      const float* __restrict__ b3, float* __restrict__ out, int n_nodes){
  __shared__ short xsh[16][72];
  __shared__ short xsl[16][72];
  __shared__ float z1[16][650];   // 650: conflict-free kg groups
  __shared__ float z2[16][10];
  int n0 = blockIdx.x * 16;
  int t  = threadIdx.x;
  for (int i = t; i < 16 * 64; i += 256){
    int r = i >> 6, c = i & 63;
    int nn = n0 + r;
    float v = (nn < n_nodes) ? xo[(size_t)nn * 64 + c] : 0.f;
    unsigned short hu = f2b_rne(v);
    float lof = v - us2f(hu);
    xsh[r][c] = (short)hu;
    xsl[r][c] = (short)f2b_rne(lof);
  }
  __syncthreads();
  int wid = t >> 6, lane = t & 63;
  int rowa = lane & 15, kg = lane >> 4, cl = lane & 15;
  short8 ah[2], al[2];
  #pragma unroll
  for (int ks = 0; ks < 2; ks++){
    ah[ks] = *reinterpret_cast<const short8*>(&xsh[rowa][ks * 32 + kg * 8]);
    al[ks] = *reinterpret_cast<const short8*>(&xsl[rowa][ks * 32 + kg * 8]);
  }
  for (int f0 = 0; f0 < 10; f0++){
    int f = wid * 10 + f0;
    f32x4 acc = {0.f, 0.f, 0.f, 0.f};
    #pragma unroll
    for (int ks = 0; ks < 2; ks++){
      short8 b_h = *reinterpret_cast<const short8*>(Bp3 + ((size_t)(ks * 40) + f) * 512 + lane * 8);
      short8 b_l = *reinterpret_cast<const short8*>(Bp3 + ((size_t)((2 + ks) * 40) + f) * 512 + lane * 8);
      acc = mfma16(ah[ks], b_h, acc);
      acc = mfma16(al[ks], b_h, acc);
      acc = mfma16(ah[ks], b_l, acc);
    }
    int cc = f * 16 + cl;
    float bb = b1[cc];
    #pragma unroll
    for (int reg = 0; reg < 4; reg++)
      z1[kg * 4 + reg][cc] = fmaxf(acc[reg] + bb, 0.f);
  }
  __syncthreads();
  {
    int g = t >> 4, sub = t & 15;
    float p[10];
    #pragma unroll
    for (int kk = 0; kk < 10; kk++) p[kk] = 0.f;
    for (int jj = 0; jj < 40; jj++){
      int j = sub + jj * 16;
      float v = z1[g][j];
      #pragma unroll
      for (int kk = 0; kk < 10; kk++) p[kk] += v * W2[j * 10 + kk];
    }
    #pragma unroll
    for (int kk = 0; kk < 10; kk++){
      #pragma unroll
      for (int m = 8; m; m >>= 1) p[kk] += __shfl_xor(p[kk], m);
    }
    if (sub == 0){
      #pragma unroll
      for (int kk = 0; kk < 10; kk++) z2[g][kk] = fmaxf(p[kk] + b2[kk], 0.f);
    }
  }
  __syncthreads();
  if (t < 16){
    int nn = n0 + t;
    if (nn < n_nodes){
      float acc = b3[0];
      #pragma unroll
      for (int kk = 0; kk < 10; kk++) acc += z2[t][kk] * W3[kk];
      out[nn] = 1.f / (1.f + __expf(-acc));
    }
  }
}

extern "C" void kernel_launch(void* const* d_in, const int* in_sizes, int n_in,
                              void* d_out, int out_size, void* d_ws, size_t ws_size,
                              hipStream_t stream){
  const float* x    = (const float*)d_in[0];
  const int*   ei   = (const int*)  d_in[1];
  const float* Watt = (const float*)d_in[2];
  const float* aatt = (const float*)d_in[3];
  const float* Wout = (const float*)d_in[4];
  const float* aout = (const float*)d_in[5];
  const float* W1   = (const float*)d_in[6];
  const float* b1   = (const float*)d_in[7];
  const float* W2   = (const float*)d_in[8];
  const float* b2   = (const float*)d_in[9];
  const float* W3   = (const float*)d_in[10];
  const float* b3   = (const float*)d_in[11];
  float* out = (float*)d_out;

  int N = in_sizes[0] / NF;
  int E = in_sizes[1] / 2;
  const int* row = ei;
  const int* col = ei + E;

  char* base = (char*)d_ws;
  size_t off = 0;
  auto alloc = [&](size_t bytes) -> void* {
    void* p = base + off;
    off = (off + bytes + 255) & ~(size_t)255;
    return p;
  };
  short* xb     = (short*)alloc((size_t)N * 64 * 2);   // 12.8 MB bf16 x (L2-resident gather target)
  bf16*  h2b    = (bf16*) alloc((size_t)N * 64 * 2);   // 12.8 MB
  float* xo     = (float*)alloc((size_t)N * 64 * 4);   // 25.6 MB
  float* a1s    = (float*)alloc((size_t)N * NH * 4);
  float* a1d    = (float*)alloc((size_t)N * NH * 4);
  float* a2s    = (float*)alloc((size_t)N * 4);
  float* a2d    = (float*)alloc((size_t)N * 4);
  int*   cnt    = (int*)  alloc((size_t)N * 4);
  int*   rowptr = (int*)  alloc((size_t)N * 4);
  int*   wptr   = (int*)  alloc((size_t)N * 4);
  int*   incl   = (int*)  alloc((size_t)N * 4);
  int    NB     = (N + 1023) / 1024;
  int*   bsum   = (int*)  alloc((size_t)NB * 4);
  int*   boff   = (int*)  alloc((size_t)NB * 4);
  int*   scol   = (int*)  alloc((size_t)E * 4);        // 6.4 MB
  short* Bp1    = (short*)alloc((size_t)4 * 33 * 512 * 2);   // 135 KB packed W_att|alpha1
  short* Bp2    = (short*)alloc((size_t)32 * 5 * 512 * 2);   // 160 KB packed Wout|alpha2
  short* Bp3    = (short*)alloc((size_t)4 * 40 * 512 * 2);   // 160 KB packed W1
  (void)ws_size; (void)n_in; (void)out_size;

  hipMemsetAsync(cnt, 0, (size_t)N * 4, stream);

  k_prep1     <<<66,              64, 0, stream>>>(Watt, aatt, Bp1);
  k_prep2     <<<80,              64, 0, stream>>>(Wout, aout, Bp2);
  k_prep3     <<<80,              64, 0, stream>>>(W1, Bp3);
  k_prep_x    <<<(N + 15) / 16,  256, 0, stream>>>(x, Bp1, xb, a1s, a1d, N);
  k_count     <<<(E + 255) / 256, 256, 0, stream>>>(row, cnt, E);
  k_scan_a    <<<NB,             1024, 0, stream>>>(cnt, incl, bsum, N);
  k_scan_b    <<<1,               128, 0, stream>>>(bsum, boff, NB);
  k_scan_c    <<<NB,             1024, 0, stream>>>(incl, cnt, boff, rowptr, wptr, N);
  k_scatter   <<<(E + 255) / 256, 256, 0, stream>>>(row, col, wptr, scol, E);
  k_agg1_gemm2<<<(N + 7) / 8,     512, 0, stream>>>(xb, a1s, a1d, rowptr, cnt, scol,
                                                    Bp1, Bp2, h2b, a2s, a2d, N);
  k_agg2      <<<(N + 31) / 32,  256, 0, stream>>>(h2b, a2s, a2d, rowptr, cnt, scol, xo, N);
  k_mlp       <<<(N + 15) / 16,  256, 0, stream>>>(xo, Bp3, b1, W2, b2, W3, b3, out, N);
}

// Round 8
// 681.060 us; speedup vs baseline: 1.2196x; 1.0190x over previous
//
#include <hip/hip_runtime.h>
#include <hip/hip_bf16.h>
#include <math.h>

#define NF 64
#define NH 8
#define SLOPE 0.2f

typedef __hip_bfloat16 bf16;
typedef short short8 __attribute__((ext_vector_type(8)));
typedef unsigned int u32x2 __attribute__((ext_vector_type(2)));
typedef unsigned int uint4v __attribute__((ext_vector_type(4)));
typedef float f32x4 __attribute__((ext_vector_type(4)));
typedef float f32x2 __attribute__((ext_vector_type(2)));

__device__ __forceinline__ float b2f(bf16 v){ return __bfloat162float(v); }
__device__ __forceinline__ bf16 f2b(float v){ return __float2bfloat16(v); }
__device__ __forceinline__ float us2f(unsigned short u){
  union{ unsigned int i; float f; } c; c.i = ((unsigned int)u) << 16; return c.f;
}
// unpack packed 2xbf16 dword -> f32 (low / high element)
__device__ __forceinline__ float lo16(unsigned int u){
  union{ unsigned int i; float f; } c; c.i = u << 16; return c.f;
}
__device__ __forceinline__ float hi16(unsigned int u){
  union{ unsigned int i; float f; } c; c.i = u & 0xFFFF0000u; return c.f;
}
// round-to-nearest-even f32 -> bf16 bits
__device__ __forceinline__ unsigned short f2b_rne(float v){
  union{ float f; unsigned int i; } c; c.f = v;
  unsigned int b = c.i + 0x7FFF + ((c.i >> 16) & 1);
  return (unsigned short)(b >> 16);
}
__device__ __forceinline__ f32x4 mfma16(short8 a, short8 b, f32x4 c){
  return __builtin_amdgcn_mfma_f32_16x16x32_bf16(a, b, c, 0, 0, 0);
}

// ---------- weight pre-pack kernels (tiny, run once per launch) ----------
// B-fragment layout for mfma_f32_16x16x32_bf16: b[j] = B[(lane>>4)*8+j][lane&15]
// Packed as [term(hi=0,lo=1)][ks][frag][lane][j] -> coalesced short8 per lane.

// GEMM1: B = [W_att heads (512 cols) | W@a_src (8) | W@a_dst (8)] : 64 x 528, 33 frags, 2 ks
// frags 0..31 double as the per-head W fragments for agg1's phase-2a (head w = frags 4w..4w+3).
__global__ void k_prep1(const float* __restrict__ Watt, const float* __restrict__ aatt,
                        short* __restrict__ Bp1){
  int f = blockIdx.x >> 1, ks = blockIdx.x & 1;
  int lane = threadIdx.x;
  int kg = lane >> 4, cl = lane & 15;
  int col = f * 16 + cl;
  for (int j = 0; j < 8; j++){
    int k = ks * 32 + kg * 8 + j;
    float val;
    if (col < 512){
      val = Watt[(size_t)(col >> 6) * 4096 + k * 64 + (col & 63)];
    } else {
      int h = (col - 512) & 7;
      const float* arow = aatt + h * 128 + ((col >= 520) ? 64 : 0);
      const float* wrow = Watt + (size_t)h * 4096 + k * 64;
      float s = 0.f;
      for (int d = 0; d < 64; d++) s += wrow[d] * arow[d];
      val = s;
    }
    unsigned short hu = f2b_rne(val);
    float lof = val - us2f(hu);
    Bp1[((size_t)(ks * 33) + f) * 512 + lane * 8 + j]       = (short)hu;
    Bp1[((size_t)((2 + ks) * 33) + f) * 512 + lane * 8 + j] = (short)f2b_rne(lof);
  }
}

// GEMM2: B = [Wout (64 cols) | Wout@aout_s | Wout@aout_d | pad] : 512 x 80, 5 frags, 16 ks
__global__ void k_prep2(const float* __restrict__ Wout, const float* __restrict__ aout,
                        short* __restrict__ Bp2){
  int f = blockIdx.x >> 4, ks = blockIdx.x & 15;
  int lane = threadIdx.x;
  int kg = lane >> 4, cl = lane & 15;
  int col = f * 16 + cl;
  for (int j = 0; j < 8; j++){
    int k = ks * 32 + kg * 8 + j;
    float val = 0.f;
    if (col < 64){
      val = Wout[(size_t)k * 64 + col];
    } else if (col == 64 || col == 65){
      const float* arow = aout + ((col == 65) ? 64 : 0);
      const float* wrow = Wout + (size_t)k * 64;
      float s = 0.f;
      for (int d = 0; d < 64; d++) s += wrow[d] * arow[d];
      val = s;
    }
    unsigned short hu = f2b_rne(val);
    float lof = val - us2f(hu);
    Bp2[((size_t)(ks * 5) + f) * 512 + lane * 8 + j]        = (short)hu;
    Bp2[((size_t)((16 + ks) * 5) + f) * 512 + lane * 8 + j] = (short)f2b_rne(lof);
  }
}

// MLP1: B = W1 : 64 x 640, 40 frags, 2 ks
__global__ void k_prep3(const float* __restrict__ W1, short* __restrict__ Bp3){
  int f = blockIdx.x >> 1, ks = blockIdx.x & 1;
  int lane = threadIdx.x;
  int kg = lane >> 4, cl = lane & 15;
  int col = f * 16 + cl;
  for (int j = 0; j < 8; j++){
    int k = ks * 32 + kg * 8 + j;
    float val = W1[(size_t)k * 640 + col];
    unsigned short hu = f2b_rne(val);
    float lof = val - us2f(hu);
    Bp3[((size_t)(ks * 40) + f) * 512 + lane * 8 + j]       = (short)hu;
    Bp3[((size_t)((2 + ks) * 40) + f) * 512 + lane * 8 + j] = (short)f2b_rne(lof);
  }
}

// ---------- prep_x: xb = bf16(x) (gather payload for agg1) + alpha1 GEMM ----------
__global__ void __launch_bounds__(256)
k_prep_x(const float* __restrict__ x, const short* __restrict__ Bp1,
         short* __restrict__ xb, float* __restrict__ a1s, float* __restrict__ a1d,
         int n_nodes){
  __shared__ short xsh[16][72];   // hi bf16
  __shared__ short xsl[16][72];   // lo bf16
  int n0 = blockIdx.x * 16;
  int t = threadIdx.x;
  for (int i = t; i < 16 * 64; i += 256){
    int r = i >> 6, c = i & 63;
    int nn = n0 + r;
    float v = (nn < n_nodes) ? x[(size_t)nn * NF + c] : 0.f;
    unsigned short hu = f2b_rne(v);
    float lof = v - us2f(hu);
    xsh[r][c] = (short)hu;
    xsl[r][c] = (short)f2b_rne(lof);
  }
  __syncthreads();
  // coalesced xb write (hi bf16 only: gather payload)
  for (int i = t; i < 16 * 8; i += 256){
    int r = i >> 3, c8 = (i & 7) * 8;
    int nn = n0 + r;
    if (nn < n_nodes)
      *reinterpret_cast<short8*>(xb + (size_t)nn * 64 + c8) =
        *reinterpret_cast<const short8*>(&xsh[r][c8]);
  }
  int wid = t >> 6, lane = t & 63;
  if (wid == 3){                       // alpha frag (f=32): 16 alpha cols
    int rowa = lane & 15, kg = lane >> 4, cl = lane & 15;
    short8 ah[2], al[2];
    #pragma unroll
    for (int ks = 0; ks < 2; ks++){
      ah[ks] = *reinterpret_cast<const short8*>(&xsh[rowa][ks * 32 + kg * 8]);
      al[ks] = *reinterpret_cast<const short8*>(&xsl[rowa][ks * 32 + kg * 8]);
    }
    f32x4 acc = {0.f, 0.f, 0.f, 0.f};
    #pragma unroll
    for (int ks = 0; ks < 2; ks++){
      short8 b_h = *reinterpret_cast<const short8*>(Bp1 + ((size_t)(ks * 33) + 32) * 512 + lane * 8);
      short8 b_l = *reinterpret_cast<const short8*>(Bp1 + ((size_t)((2 + ks) * 33) + 32) * 512 + lane * 8);
      acc = mfma16(ah[ks], b_h, acc);
      acc = mfma16(al[ks], b_h, acc);
      acc = mfma16(ah[ks], b_l, acc);
    }
    #pragma unroll
    for (int reg = 0; reg < 4; reg++){
      int nn = n0 + kg * 4 + reg;
      if (nn < n_nodes){
        if (cl < 8) a1s[nn * NH + cl] = acc[reg];
        else        a1d[nn * NH + (cl - 8)] = acc[reg];
      }
    }
  }
}

// ---------- CSR build ----------
__global__ void k_count(const int* __restrict__ row, int* __restrict__ cnt, int E){
  int e = blockIdx.x * blockDim.x + threadIdx.x;
  if (e < E) atomicAdd(&cnt[row[e]], 1);
}

__global__ void k_scan_a(const int* __restrict__ cnt, int* __restrict__ incl,
                         int* __restrict__ bsum, int n){
  __shared__ int s[1024];
  int i = blockIdx.x * 1024 + threadIdx.x;
  int v = (i < n) ? cnt[i] : 0;
  s[threadIdx.x] = v;
  __syncthreads();
  for (int d = 1; d < 1024; d <<= 1){
    int tv = (threadIdx.x >= d) ? s[threadIdx.x - d] : 0;
    __syncthreads();
    s[threadIdx.x] += tv;
    __syncthreads();
  }
  if (i < n) incl[i] = s[threadIdx.x];
  if (threadIdx.x == 1023) bsum[blockIdx.x] = s[1023];
}

__global__ void k_scan_b(const int* __restrict__ bsum, int* __restrict__ boff, int nb){
  __shared__ int s[128];
  int t = threadIdx.x;
  if (nb <= 128){
    int v = (t < nb) ? bsum[t] : 0;
    s[t] = v;
    __syncthreads();
    for (int d = 1; d < 128; d <<= 1){
      int tv = (t >= d) ? s[t - d] : 0;
      __syncthreads();
      s[t] += tv;
      __syncthreads();
    }
    if (t < nb) boff[t] = s[t] - v;   // exclusive
  } else if (t == 0){
    int run = 0;
    for (int b = 0; b < nb; b++){ boff[b] = run; run += bsum[b]; }
  }
}

__global__ void k_scan_c(const int* __restrict__ incl, const int* __restrict__ cnt,
                         const int* __restrict__ boff, int* __restrict__ rowptr,
                         int* __restrict__ wptr, int n){
  int i = blockIdx.x * 1024 + threadIdx.x;
  if (i < n){
    int start = incl[i] - cnt[i] + boff[blockIdx.x];
    rowptr[i] = start;
    wptr[i]   = start;
  }
}

__global__ void k_scatter(const int* __restrict__ row, const int* __restrict__ col,
                          int* __restrict__ wptr, int* __restrict__ scol, int E){
  int e = blockIdx.x * blockDim.x + threadIdx.x;
  if (e < E){
    int r = row[e];
    int pos = atomicAdd(&wptr[r], 1);
    scol[pos] = col[e];
  }
}

// ---------- fused agg1 (input-side) + per-head W MFMA + Wout MFMA ----------
// 8 nodes/block, 512 threads (8 waves), 1 node/wave.
// Phase 1: G[h][feat] = sum_c e_c^h * xb[c][feat]; G stored bf16 (single short8 b128 store).
// Phase 2a: h'_head = (G_h/rsum) @ W_head, 2 MFMAs/frag (bf16 A, hi+lo W), ELU -> xh bf16.
// Phase 2b: Wout GEMM, 2 MFMAs/step (bf16 A, hi+lo W), alpha2 folded.
// Precision note: bf16-only intermediates in the feature path are backed by the round-5
// measurement that fp8 (~3%/elem) H left absmax unchanged; bf16 is ~0.4%/elem.
__global__ void __launch_bounds__(512, 2)
k_agg1_gemm2(const short* __restrict__ xb, const float* __restrict__ a1s,
             const float* __restrict__ a1d, const int* __restrict__ rowptr,
             const int* __restrict__ cnt, const int* __restrict__ scol,
             const short* __restrict__ Bp1, const short* __restrict__ Bp2,
             bf16* __restrict__ h2b, float* __restrict__ a2s,
             float* __restrict__ a2d, int n_nodes){
  __shared__ short Gh[8 * 600];  // [node][h*72 + feat] bf16; stride 600: conflict-free frag reads
  __shared__ short xh[8][528];   // elu(h') bf16
  int n0   = blockIdx.x * 8;
  int wid  = threadIdx.x >> 6;
  int lane = threadIdx.x & 63;
  int h = lane >> 3, q = lane & 7;
  int n = n0 + wid;
  int gidx = wid * 600 + h * 72 + q * 8;

  if (n < n_nodes){
    float asrc = a1s[n * NH + h];
    int beg = rowptr[n], endk = beg + cnt[n];
    f32x2 acc2[4] = {{0.f,0.f},{0.f,0.f},{0.f,0.f},{0.f,0.f}};
    float rsum = 0.f;
    int k = beg;
    for (; k + 3 < endk; k += 4){
      int c0 = scol[k], c1 = scol[k + 1], c2 = scol[k + 2], c3 = scol[k + 3];
      uint4v x0 = *reinterpret_cast<const uint4v*>(xb + (size_t)c0 * 64 + q * 8);
      uint4v x1 = *reinterpret_cast<const uint4v*>(xb + (size_t)c1 * 64 + q * 8);
      uint4v x2 = *reinterpret_cast<const uint4v*>(xb + (size_t)c2 * 64 + q * 8);
      uint4v x3 = *reinterpret_cast<const uint4v*>(xb + (size_t)c3 * 64 + q * 8);
      float s0 = asrc + a1d[c0 * NH + h];
      float s1 = asrc + a1d[c1 * NH + h];
      float s2 = asrc + a1d[c2 * NH + h];
      float s3 = asrc + a1d[c3 * NH + h];
      float l0 = fmaxf(s0, SLOPE * s0);
      float l1 = fmaxf(s1, SLOPE * s1);
      float l2 = fmaxf(s2, SLOPE * s2);
      float l3 = fmaxf(s3, SLOPE * s3);
      float e0 = __expf(-l0);
      float e1 = __expf(-l1);
      float e2 = __expf(-l2);
      float e3 = __expf(-l3);
      rsum += (e0 + e1) + (e2 + e3);
      f32x2 ev0 = {e0, e0}, ev1 = {e1, e1}, ev2 = {e2, e2}, ev3 = {e3, e3};
      #pragma unroll
      for (int d = 0; d < 4; d++){
        f32x2 hv0 = {lo16(x0[d]), hi16(x0[d])};
        f32x2 hv1 = {lo16(x1[d]), hi16(x1[d])};
        f32x2 hv2 = {lo16(x2[d]), hi16(x2[d])};
        f32x2 hv3 = {lo16(x3[d]), hi16(x3[d])};
        acc2[d] += (ev0 * hv0 + ev1 * hv1) + (ev2 * hv2 + ev3 * hv3);
      }
    }
    for (; k < endk; ++k){
      int c0 = scol[k];
      uint4v x0 = *reinterpret_cast<const uint4v*>(xb + (size_t)c0 * 64 + q * 8);
      float s0 = asrc + a1d[c0 * NH + h];
      float l0 = fmaxf(s0, SLOPE * s0);
      float e0 = __expf(-l0);
      rsum += e0;
      f32x2 ev0 = {e0, e0};
      #pragma unroll
      for (int d = 0; d < 4; d++){
        f32x2 hv0 = {lo16(x0[d]), hi16(x0[d])};
        acc2[d] += ev0 * hv0;
      }
    }
    float inv = 1.f / rsum;
    short8 hv8;
    #pragma unroll
    for (int jj = 0; jj < 8; jj++)
      hv8[jj] = (short)f2b_rne(acc2[jj >> 1][jj & 1] * inv);
    *reinterpret_cast<short8*>(&Gh[gidx]) = hv8;
  } else {
    short8 z = {0,0,0,0,0,0,0,0};
    *reinterpret_cast<short8*>(&Gh[gidx]) = z;
  }
  __syncthreads();

  // ---- phase 2a: per-head W GEMM; wave w = head w; ELU epilogue -> xh ----
  {
    int rowa = lane & 7;            // A rows 8-15 duplicate 0-7 (outputs discarded)
    int kg   = lane >> 4, cl = lane & 15;
    short8 gah[2];
    #pragma unroll
    for (int ks = 0; ks < 2; ks++)
      gah[ks] = *reinterpret_cast<const short8*>(&Gh[rowa * 600 + wid * 72 + ks * 32 + kg * 8]);
    #pragma unroll
    for (int fc = 0; fc < 4; fc++){
      int f = wid * 4 + fc;
      f32x4 acc = {0.f, 0.f, 0.f, 0.f};
      #pragma unroll
      for (int ks = 0; ks < 2; ks++){
        short8 b_h = *reinterpret_cast<const short8*>(Bp1 + ((size_t)(ks * 33) + f) * 512 + lane * 8);
        short8 b_l = *reinterpret_cast<const short8*>(Bp1 + ((size_t)((2 + ks) * 33) + f) * 512 + lane * 8);
        acc = mfma16(gah[ks], b_h, acc);
        acc = mfma16(gah[ks], b_l, acc);
      }
      if (kg < 2){                  // D rows 0-7 = the 8 nodes
        #pragma unroll
        for (int reg = 0; reg < 4; reg++){
          int r = kg * 4 + reg;
          float v = acc[reg];
          v = (v > 0.f) ? v : (__expf(v) - 1.f);   // elu
          xh[r][wid * 64 + fc * 16 + cl] = (short)f2b_rne(v);
        }
      }
    }
  }
  __syncthreads();

  // ---- phase 2b: Wout MFMA; waves 0-3 -> h2b cols, wave 4 -> alpha2 ----
  if (wid < 5){
    int rowa = lane & 7;
    int kg   = lane >> 4;
    f32x4 acc = {0.f, 0.f, 0.f, 0.f};
    #pragma unroll 4
    for (int ks = 0; ks < 16; ks++){
      short8 a_h = *reinterpret_cast<const short8*>(&xh[rowa][ks * 32 + kg * 8]);
      short8 b_h = *reinterpret_cast<const short8*>(Bp2 + ((size_t)(ks * 5) + wid) * 512 + lane * 8);
      short8 b_l = *reinterpret_cast<const short8*>(Bp2 + ((size_t)((16 + ks) * 5) + wid) * 512 + lane * 8);
      acc = mfma16(a_h, b_h, acc);
      acc = mfma16(a_h, b_l, acc);
    }
    int cl = lane & 15;
    if (kg < 2){
      #pragma unroll
      for (int reg = 0; reg < 4; reg++){
        int nn = n0 + kg * 4 + reg;
        if (nn < n_nodes){
          if (wid < 4){
            h2b[(size_t)nn * 64 + wid * 16 + cl] = f2b(acc[reg]);
          } else if (cl == 0){
            a2s[nn] = acc[reg];
          } else if (cl == 1){
            a2d[nn] = acc[reg];
          }
        }
      }
    }
  }
}

// ---------- aggregation layer 2: 8 nodes/wave, 8-lane groups, 16B row slices ----------
__global__ void __launch_bounds__(256)
k_agg2(const bf16* __restrict__ h2b, const float* __restrict__ a2s,
       const float* __restrict__ a2d, const int* __restrict__ rowptr,
       const int* __restrict__ cnt, const int* __restrict__ scol,
       float* __restrict__ xo, int n_nodes){
  int wid  = threadIdx.x >> 6;
  int lane = threadIdx.x & 63;
  int g = lane >> 3, sl = lane & 7;
  int n = blockIdx.x * 32 + wid * 8 + g;
  bool nv = (n < n_nodes);
  int beg = 0, deg = 0;
  float asrc = 0.f;
  if (nv){ beg = rowptr[n]; deg = cnt[n]; asrc = a2s[n]; }
  int mdeg = deg;
  #pragma unroll
  for (int m = 8; m < 64; m <<= 1){
    int o = __shfl_xor(mdeg, m);
    mdeg = (o > mdeg) ? o : mdeg;
  }
  f32x2 acc2[4] = {{0.f,0.f},{0.f,0.f},{0.f,0.f},{0.f,0.f}};
  float rsum = 0.f;
  int it = 0;
  for (; it + 1 < mdeg; it += 2){
    int i0 = (it     < deg) ? it     : 0;
    int i1 = (it + 1 < deg) ? it + 1 : 0;
    int c0 = scol[beg + i0];
    int c1 = scol[beg + i1];
    uint4v h0 = *reinterpret_cast<const uint4v*>(h2b + ((size_t)c0 << 6) + sl * 8);
    uint4v h1 = *reinterpret_cast<const uint4v*>(h2b + ((size_t)c1 << 6) + sl * 8);
    float s0 = asrc + a2d[c0];
    float s1 = asrc + a2d[c1];
    float l0 = fmaxf(s0, SLOPE * s0);
    float l1 = fmaxf(s1, SLOPE * s1);
    float e0 = __expf(-l0);
    float e1 = __expf(-l1);
    e0 = (it     < deg) ? e0 : 0.f;
    e1 = (it + 1 < deg) ? e1 : 0.f;
    rsum += e0 + e1;
    f32x2 ev0 = {e0, e0}, ev1 = {e1, e1};
    #pragma unroll
    for (int d = 0; d < 4; d++){
      f32x2 hv0 = {lo16(h0[d]), hi16(h0[d])};
      f32x2 hv1 = {lo16(h1[d]), hi16(h1[d])};
      acc2[d] += ev0 * hv0 + ev1 * hv1;
    }
  }
  if (it < mdeg){
    int i0 = (it < deg) ? it : 0;
    int c0 = scol[beg + i0];
    uint4v h0 = *reinterpret_cast<const uint4v*>(h2b + ((size_t)c0 << 6) + sl * 8);
    float s0 = asrc + a2d[c0];
    float l0 = fmaxf(s0, SLOPE * s0);
    float e0 = __expf(-l0);
    e0 = (it < deg) ? e0 : 0.f;
    rsum += e0;
    f32x2 ev0 = {e0, e0};
    #pragma unroll
    for (int d = 0; d < 4; d++){
      f32x2 hv0 = {lo16(h0[d]), hi16(h0[d])};
      acc2[d] += ev0 * hv0;
    }
  }
  if (nv){
    float inv = 1.f / rsum;
    float4 lo, hi;
    float vv[8];
    #pragma unroll
    for (int jj = 0; jj < 8; jj++){
      float v = acc2[jj >> 1][jj & 1] * inv;
      vv[jj] = (v > 0.f) ? v : (__expf(v) - 1.f);   // elu after layer 2
    }
    lo.x = vv[0]; lo.y = vv[1]; lo.z = vv[2]; lo.w = vv[3];
    hi.x = vv[4]; hi.y = vv[5]; hi.z = vv[6]; hi.w = vv[7];
    *reinterpret_cast<float4*>(xo + (size_t)n * 64 + sl * 8)     = lo;
    *reinterpret_cast<float4*>(xo + (size_t)n * 64 + sl * 8 + 4) = hi;
  }
}

// ---------- MLP head: MFMA for W1 stage, 16 nodes/block ----------
__global__ void __launch_bounds__(256)
k_mlp(const float* __restrict__ xo, const short* __restrict__ Bp3,
      const float* __restrict__ b1, const float* __restrict__ W2,
      const float* __restrict__ b2, const float* __restrict__ W3,
      const float* __restrict__ b3, float* __restrict__ out, int n_nodes){
  __shared__ short xsh[16][72];
  __shared__ short xsl[16][72];
  __shared__ float z1[16][650];   // 650: conflict-free kg groups
  __shared__ float z2[16][10];
  int n0 = blockIdx.x * 16;
  int t  = threadIdx.x;
  for (int i = t; i < 16 * 64; i += 256){
    int r = i >> 6, c = i & 63;
    int nn = n0 + r;
    float v = (nn < n_nodes) ? xo[(size_t)nn * 64 + c] : 0.f;
    unsigned short hu = f2b_rne(v);
    float lof = v - us2f(hu);
    xsh[r][c] = (short)hu;
    xsl[r][c] = (short)f2b_rne(lof);
  }
  __syncthreads();
  int wid = t >> 6, lane = t & 63;
  int rowa = lane & 15, kg = lane >> 4, cl = lane & 15;
  short8 ah[2], al[2];
  #pragma unroll
  for (int ks = 0; ks < 2; ks++){
    ah[ks] = *reinterpret_cast<const short8*>(&xsh[rowa][ks * 32 + kg * 8]);
    al[ks] = *reinterpret_cast<const short8*>(&xsl[rowa][ks * 32 + kg * 8]);
  }
  for (int f0 = 0; f0 < 10; f0++){
    int f = wid * 10 + f0;
    f32x4 acc = {0.f, 0.f, 0.f, 0.f};
    #pragma unroll
    for (int ks = 0; ks < 2; ks++){
      short8 b_h = *reinterpret_cast<const short8*>(Bp3 + ((size_t)(ks * 40) + f) * 512 + lane * 8);
      short8 b_l = *reinterpret_cast<const short8*>(Bp3 + ((size_t)((2 + ks) * 40) + f) * 512 + lane * 8);
      acc = mfma16(ah[ks], b_h, acc);
      acc = mfma16(al[ks], b_h, acc);
      acc = mfma16(ah[ks], b_l, acc);
    }
    int cc = f * 16 + cl;
    float bb = b1[cc];
    #pragma unroll
    for (int reg = 0; reg < 4; reg++)
      z1[kg * 4 + reg][cc] = fmaxf(acc[reg] + bb, 0.f);
  }
  __syncthreads();
  {
    int g = t >> 4, sub = t & 15;
    float p[10];
    #pragma unroll
    for (int kk = 0; kk < 10; kk++) p[kk] = 0.f;
    for (int jj = 0; jj < 40; jj++){
      int j = sub + jj * 16;
      float v = z1[g][j];
      #pragma unroll
      for (int kk = 0; kk < 10; kk++) p[kk] += v * W2[j * 10 + kk];
    }
    #pragma unroll
    for (int kk = 0; kk < 10; kk++){
      #pragma unroll
      for (int m = 8; m; m >>= 1) p[kk] += __shfl_xor(p[kk], m);
    }
    if (sub == 0){
      #pragma unroll
      for (int kk = 0; kk < 10; kk++) z2[g][kk] = fmaxf(p[kk] + b2[kk], 0.f);
    }
  }
  __syncthreads();
  if (t < 16){
    int nn = n0 + t;
    if (nn < n_nodes){
      float acc = b3[0];
      #pragma unroll
      for (int kk = 0; kk < 10; kk++) acc += z2[t][kk] * W3[kk];
      out[nn] = 1.f / (1.f + __expf(-acc));
    }
  }
}

extern "C" void kernel_launch(void* const* d_in, const int* in_sizes, int n_in,
                              void* d_out, int out_size, void* d_ws, size_t ws_size,
                              hipStream_t stream){
  const float* x    = (const float*)d_in[0];
  const int*   ei   = (const int*)  d_in[1];
  const float* Watt = (const float*)d_in[2];
  const float* aatt = (const float*)d_in[3];
  const float* Wout = (const float*)d_in[4];
  const float* aout = (const float*)d_in[5];
  const float* W1   = (const float*)d_in[6];
  const float* b1   = (const float*)d_in[7];
  const float* W2   = (const float*)d_in[8];
  const float* b2   = (const float*)d_in[9];
  const float* W3   = (const float*)d_in[10];
  const float* b3   = (const float*)d_in[11];
  float* out = (float*)d_out;

  int N = in_sizes[0] / NF;
  int E = in_sizes[1] / 2;
  const int* row = ei;
  const int* col = ei + E;

  char* base = (char*)d_ws;
  size_t off = 0;
  auto alloc = [&](size_t bytes) -> void* {
    void* p = base + off;
    off = (off + bytes + 255) & ~(size_t)255;
    return p;
  };
  short* xb     = (short*)alloc((size_t)N * 64 * 2);   // 12.8 MB bf16 x (L2-resident gather target)
  bf16*  h2b    = (bf16*) alloc((size_t)N * 64 * 2);   // 12.8 MB
  float* xo     = (float*)alloc((size_t)N * 64 * 4);   // 25.6 MB
  float* a1s    = (float*)alloc((size_t)N * NH * 4);
  float* a1d    = (float*)alloc((size_t)N * NH * 4);
  float* a2s    = (float*)alloc((size_t)N * 4);
  float* a2d    = (float*)alloc((size_t)N * 4);
  int*   cnt    = (int*)  alloc((size_t)N * 4);
  int*   rowptr = (int*)  alloc((size_t)N * 4);
  int*   wptr   = (int*)  alloc((size_t)N * 4);
  int*   incl   = (int*)  alloc((size_t)N * 4);
  int    NB     = (N + 1023) / 1024;
  int*   bsum   = (int*)  alloc((size_t)NB * 4);
  int*   boff   = (int*)  alloc((size_t)NB * 4);
  int*   scol   = (int*)  alloc((size_t)E * 4);        // 6.4 MB
  short* Bp1    = (short*)alloc((size_t)4 * 33 * 512 * 2);   // 135 KB packed W_att|alpha1
  short* Bp2    = (short*)alloc((size_t)32 * 5 * 512 * 2);   // 160 KB packed Wout|alpha2
  short* Bp3    = (short*)alloc((size_t)4 * 40 * 512 * 2);   // 160 KB packed W1
  (void)ws_size; (void)n_in; (void)out_size;

  hipMemsetAsync(cnt, 0, (size_t)N * 4, stream);

  k_prep1     <<<66,              64, 0, stream>>>(Watt, aatt, Bp1);
  k_prep2     <<<80,              64, 0, stream>>>(Wout, aout, Bp2);
  k_prep3     <<<80,              64, 0, stream>>>(W1, Bp3);
  k_prep_x    <<<(N + 15) / 16,  256, 0, stream>>>(x, Bp1, xb, a1s, a1d, N);
  k_count     <<<(E + 255) / 256, 256, 0, stream>>>(row, cnt, E);
  k_scan_a    <<<NB,             1024, 0, stream>>>(cnt, incl, bsum, N);
  k_scan_b    <<<1,               128, 0, stream>>>(bsum, boff, NB);
  k_scan_c    <<<NB,             1024, 0, stream>>>(incl, cnt, boff, rowptr, wptr, N);
  k_scatter   <<<(E + 255) / 256, 256, 0, stream>>>(row, col, wptr, scol, E);
  k_agg1_gemm2<<<(N + 7) / 8,     512, 0, stream>>>(xb, a1s, a1d, rowptr, cnt, scol,
                                                    Bp1, Bp2, h2b, a2s, a2d, N);
  k_agg2      <<<(N + 31) / 32,  256, 0, stream>>>(h2b, a2s, a2d, rowptr, cnt, scol, xo, N);
  k_mlp       <<<(N + 15) / 16,  256, 0, stream>>>(xo, Bp3, b1, W2, b2, W3, b3, out, N);
}